// Round 1
// baseline (1476.401 us; speedup 1.0000x reference)
//
#include <hip/hip_runtime.h>
#include <hip/hip_bf16.h>
#include <cmath>

typedef __bf16 bf16x8 __attribute__((ext_vector_type(8)));
typedef __bf16 bf16x4 __attribute__((ext_vector_type(4)));
typedef float  f32x4  __attribute__((ext_vector_type(4)));

#define AS1 __attribute__((address_space(1)))
#define AS3 __attribute__((address_space(3)))
#define GLDS16(gp, lp) __builtin_amdgcn_global_load_lds((AS1 void*)(gp), (AS3 void*)(lp), 16, 0, 0)

#define B_DIM 2
#define S_LEN 2048
#define HIDDEN 4096
#define NHEADS 32
#define NKV 8
#define HDIM 128
#define QSZ 4096
#define KVSZ 1024
#define QKVSZ 6144
#define ATT_SCALE 0.0078125f   /* 1/128 */
#define L2E 1.4426950408889634f

// ---------------- f32 -> bf16 conversion (vectorized) ----------------
__global__ __launch_bounds__(256) void conv_f32_bf16(const float* __restrict__ in,
                                                     __bf16* __restrict__ out, int n4) {
    int idx = blockIdx.x * 256 + threadIdx.x;
    if (idx < n4) {
        float4 v = ((const float4*)in)[idx];
        bf16x4 o;
        o[0] = (__bf16)v.x; o[1] = (__bf16)v.y; o[2] = (__bf16)v.z; o[3] = (__bf16)v.w;
        ((bf16x4*)out)[idx] = o;
    }
}

// ---------------- RoPE cos/sin table: [pos][i], i<64 ----------------
__global__ __launch_bounds__(256) void rope_table_kernel(float* __restrict__ ct,
                                                         float* __restrict__ st) {
    int idx = blockIdx.x * 256 + threadIdx.x;   // S_LEN*64 entries
    int p = idx >> 6, i = idx & 63;
    // inv_freq = 10000^(-i/64) = exp(-i * ln(10000)/64)
    float inv = expf(-(float)i * (9.210340371976184f / 64.0f));
    float freq = (float)p * inv;
    float s, c;
    sincosf(freq, &s, &c);
    ct[idx] = c; st[idx] = s;
}

// ---------------- GEMM C[m,n] = sum_k A[m,k]*B[n,k]  (m97 structure) ----------------
// A: [M,K] bf16 row-major, B: [N,K] bf16 row-major, C: [M,N] f32. M,N mult of 128, K mult of 32.
__global__ __launch_bounds__(256) void gemm_bt(const __bf16* __restrict__ A,
                                               const __bf16* __restrict__ B,
                                               float* __restrict__ C,
                                               int N, int K) {
    __shared__ __bf16 As[128 * 32];
    __shared__ __bf16 Bs[128 * 32];
    const int tid = threadIdx.x;
    const int w = tid >> 6, l = tid & 63;
    const int l15 = l & 15, l4 = l >> 4;
    const int wr = w >> 1, wc = w & 1;
    const int m0 = blockIdx.y * 128, n0 = blockIdx.x * 128;

    f32x4 acc[4][4] = {};

    for (int kt = 0; kt < K; kt += 32) {
#pragma unroll
        for (int i = 0; i < 2; ++i) {
            int chunk = i * 256 + tid;          // 0..511
            int row = chunk >> 2;               // 0..127
            int c8 = (chunk & 3) << 3;          // 0,8,16,24
            GLDS16(A + (size_t)(m0 + row) * K + kt + c8, (char*)As + chunk * 16);
            GLDS16(B + (size_t)(n0 + row) * K + kt + c8, (char*)Bs + chunk * 16);
        }
        __syncthreads();
        bf16x8 af[4], bfr[4];
#pragma unroll
        for (int x = 0; x < 4; ++x) {
            af[x]  = *(const bf16x8*)(As + (wr * 64 + x * 16 + l15) * 32 + l4 * 8);
            bfr[x] = *(const bf16x8*)(Bs + (wc * 64 + x * 16 + l15) * 32 + l4 * 8);
        }
#pragma unroll
        for (int mi = 0; mi < 4; ++mi)
#pragma unroll
            for (int ni = 0; ni < 4; ++ni)
                acc[mi][ni] = __builtin_amdgcn_mfma_f32_16x16x32_bf16(af[mi], bfr[ni], acc[mi][ni], 0, 0, 0);
        __syncthreads();
    }
#pragma unroll
    for (int mi = 0; mi < 4; ++mi)
#pragma unroll
        for (int ni = 0; ni < 4; ++ni)
#pragma unroll
            for (int r = 0; r < 4; ++r)
                C[(size_t)(m0 + wr * 64 + mi * 16 + l4 * 4 + r) * N + n0 + wc * 64 + ni * 16 + l15] = acc[mi][ni][r];
}

// ---------------- RoPE apply: qkv f32 -> Q [B,32,S,128] bf16, K [B,8,S,128] bf16 ----------------
__global__ __launch_bounds__(256) void rope_kernel(const float* __restrict__ qkv,
                                                   const int* __restrict__ pos,
                                                   const float* __restrict__ ct,
                                                   const float* __restrict__ st,
                                                   __bf16* __restrict__ Qb,
                                                   __bf16* __restrict__ Kb) {
    const int tid = threadIdx.x;
    const int tok = blockIdx.x;                 // 0..B*S-1
    const int b = tok >> 11, s = tok & 2047;
    const int p = pos[tok];
    const float* base = qkv + (size_t)tok * QKVSZ;
    const float* cb = ct + (size_t)p * 64;
    const float* sb = st + (size_t)p * 64;
    for (int idx = tid; idx < 2560; idx += 256) {   // (32+8)*64 pairs
        int head = idx >> 6, i = idx & 63;
        float c = cb[i], sn = sb[i];
        if (head < 32) {
            float x1 = base[head * HDIM + i];
            float x2 = base[head * HDIM + 64 + i];
            size_t o = ((size_t)(b * 32 + head) * S_LEN + s) * HDIM + i;
            Qb[o]      = (__bf16)(x1 * c - x2 * sn);
            Qb[o + 64] = (__bf16)(x2 * c + x1 * sn);
        } else {
            int g = head - 32;
            float x1 = base[QSZ + g * HDIM + i];
            float x2 = base[QSZ + g * HDIM + 64 + i];
            size_t o = ((size_t)(b * 8 + g) * S_LEN + s) * HDIM + i;
            Kb[o]      = (__bf16)(x1 * c - x2 * sn);
            Kb[o + 64] = (__bf16)(x2 * c + x1 * sn);
        }
    }
}

// ---------------- V transpose: qkv f32 V-slice -> Vt [B,8,128,S] bf16 ----------------
__global__ __launch_bounds__(256) void vtrans_kernel(const float* __restrict__ qkv,
                                                     __bf16* __restrict__ Vt) {
    __shared__ __bf16 T[64][132];
    const int tid = threadIdx.x;
    const int st = blockIdx.x, g = blockIdx.y, b = blockIdx.z;
    const float* src = qkv + ((size_t)(b * S_LEN + st * 64)) * QKVSZ + (QSZ + KVSZ) + g * HDIM;
#pragma unroll
    for (int it = 0; it < 8; ++it) {
        int c = it * 256 + tid;       // 0..2047, 32 float4-chunks per row
        int row = c >> 5;
        int c4 = c & 31;
        float4 v = *(const float4*)(src + (size_t)row * QKVSZ + c4 * 4);
        bf16x4 o;
        o[0] = (__bf16)v.x; o[1] = (__bf16)v.y; o[2] = (__bf16)v.z; o[3] = (__bf16)v.w;
        *(bf16x4*)(&T[row][c4 * 4]) = o;
    }
    __syncthreads();
#pragma unroll
    for (int it = 0; it < 8; ++it) {
        int c = it * 256 + tid;       // 0..2047, 16 chunks (of 4 s-cols) per d-row
        int d = c >> 4;
        int s4 = (c & 15) * 4;
        bf16x4 o;
        o[0] = T[s4 + 0][d]; o[1] = T[s4 + 1][d]; o[2] = T[s4 + 2][d]; o[3] = T[s4 + 3][d];
        *(bf16x4*)(Vt + ((size_t)(b * 8 + g) * HDIM + d) * S_LEN + st * 64 + s4) = o;
    }
}

// ---------------- Flash attention (causal, GQA rep=4) ----------------
// Q [B,32,S,128], K [B,8,S,128], Vt [B,8,128,S] bf16 -> O (attn) [B,S,4096] bf16
// grid (S/64, 32, B), block 256. Each wave owns 16 q-rows; K/V read direct from global (L2-fit).
__global__ __launch_bounds__(256) void attn_kernel(const __bf16* __restrict__ Q,
                                                   const __bf16* __restrict__ K,
                                                   const __bf16* __restrict__ Vt,
                                                   __bf16* __restrict__ O) {
    const int tid = threadIdx.x;
    const int w = tid >> 6, l = tid & 63;
    const int l15 = l & 15, l4 = l >> 4;
    const int qt = blockIdx.x, h = blockIdx.y, b = blockIdx.z;
    const int g = h >> 2;
    const int q0 = qt * 64 + w * 16;

    __shared__ __bf16 Pl[4][16][72];

    const __bf16* Qp = Q + ((size_t)((b * 32 + h) * S_LEN + q0)) * HDIM;
    const __bf16* Kp = K + (size_t)(b * 8 + g) * S_LEN * HDIM;
    const __bf16* Vp = Vt + (size_t)(b * 8 + g) * HDIM * S_LEN;

    bf16x8 qf[4];
#pragma unroll
    for (int kk = 0; kk < 4; ++kk)
        qf[kk] = *(const bf16x8*)(Qp + (size_t)l15 * HDIM + kk * 32 + l4 * 8);

    f32x4 acc[8] = {};
    float m[4]    = {-1e30f, -1e30f, -1e30f, -1e30f};
    float lsum[4] = {0.f, 0.f, 0.f, 0.f};

    const int nkt = qt + 1;
    for (int kt = 0; kt < nkt; ++kt) {
        // ---- scores: S = Q K^T ----
        f32x4 sfr[4];
#pragma unroll
        for (int fn = 0; fn < 4; ++fn) {
            f32x4 sa = {};
#pragma unroll
            for (int kk = 0; kk < 4; ++kk) {
                bf16x8 kb = *(const bf16x8*)(Kp + (size_t)(kt * 64 + fn * 16 + l15) * HDIM + kk * 32 + l4 * 8);
                sa = __builtin_amdgcn_mfma_f32_16x16x32_bf16(qf[kk], kb, sa, 0, 0, 0);
            }
            sfr[fn] = sa;
        }
        const bool last = (kt == nkt - 1);
        float pv[4][4];
#pragma unroll
        for (int r = 0; r < 4; ++r) {
            const int row = q0 + l4 * 4 + r;
            float sv[4];
            float best = -1e30f;
#pragma unroll
            for (int fn = 0; fn < 4; ++fn) {
                int col = kt * 64 + fn * 16 + l15;
                float v = sfr[fn][r] * ATT_SCALE;
                if (last && col > row) v = -1e30f;
                sv[fn] = v;
                best = fmaxf(best, v);
            }
#pragma unroll
            for (int off = 1; off < 16; off <<= 1)
                best = fmaxf(best, __shfl_xor(best, off));
            float mn = fmaxf(m[r], best);
            float alpha = exp2f((m[r] - mn) * L2E);
            m[r] = mn;
            float rs = 0.f;
#pragma unroll
            for (int fn = 0; fn < 4; ++fn) {
                float p = exp2f((sv[fn] - mn) * L2E);
                pv[fn][r] = p;
                rs += p;
            }
#pragma unroll
            for (int off = 1; off < 16; off <<= 1)
                rs += __shfl_xor(rs, off);
            lsum[r] = lsum[r] * alpha + rs;
#pragma unroll
            for (int n = 0; n < 8; ++n) acc[n][r] *= alpha;
        }
        // ---- P -> LDS (per-wave, transposed into A-fragment layout) ----
#pragma unroll
        for (int fn = 0; fn < 4; ++fn)
#pragma unroll
            for (int r = 0; r < 4; ++r)
                Pl[w][l4 * 4 + r][fn * 16 + l15] = (__bf16)pv[fn][r];
        asm volatile("s_waitcnt lgkmcnt(0)" ::: "memory");
        // ---- PV ----
#pragma unroll
        for (int kk = 0; kk < 2; ++kk) {
            bf16x8 pa = *(const bf16x8*)(&Pl[w][l15][kk * 32 + l4 * 8]);
#pragma unroll
            for (int n = 0; n < 8; ++n) {
                bf16x8 vb = *(const bf16x8*)(Vp + (size_t)(n * 16 + l15) * S_LEN + kt * 64 + kk * 32 + l4 * 8);
                acc[n] = __builtin_amdgcn_mfma_f32_16x16x32_bf16(pa, vb, acc[n], 0, 0, 0);
            }
        }
    }
    // ---- epilogue: attn[b, row, h*128 + d] ----
#pragma unroll
    for (int n = 0; n < 8; ++n)
#pragma unroll
        for (int r = 0; r < 4; ++r) {
            int row = q0 + l4 * 4 + r;
            O[((size_t)(b * S_LEN) + row) * QSZ + h * HDIM + n * 16 + l15] = (__bf16)(acc[n][r] / lsum[r]);
        }
}

extern "C" void kernel_launch(void* const* d_in, const int* in_sizes, int n_in,
                              void* d_out, int out_size, void* d_ws, size_t ws_size,
                              hipStream_t stream) {
    const int*   pos    = (const int*)d_in[0];
    const float* hidden = (const float*)d_in[1];
    const float* wqkv   = (const float*)d_in[2];
    const float* wo     = (const float*)d_in[3];
    float* out = (float*)d_out;

    // workspace carve (bytes total ~303 MB)
    __bf16* hb    = (__bf16*)d_ws;                     // 16,777,216 elems
    __bf16* wqb   = hb  + 16777216;                    // 25,165,824
    __bf16* wob   = wqb + 25165824;                    // 16,777,216
    float*  qkv   = (float*)(wob + 16777216);          // 25,165,824 f32
    __bf16* Qb    = (__bf16*)(qkv + 25165824);         // 16,777,216
    __bf16* Kb    = Qb  + 16777216;                    // 4,194,304
    __bf16* Vtb   = Kb  + 4194304;                     // 4,194,304
    __bf16* attnb = Vtb + 4194304;                     // 16,777,216
    float*  rc    = (float*)(attnb + 16777216);        // 131,072
    float*  rs    = rc + 131072;                       // 131,072

    // 1. convert inputs to bf16
    conv_f32_bf16<<<16384, 256, 0, stream>>>(hidden, hb, 4194304);
    conv_f32_bf16<<<24576, 256, 0, stream>>>(wqkv, wqb, 6291456);
    conv_f32_bf16<<<16384, 256, 0, stream>>>(wo, wob, 4194304);
    // 2. rope table
    rope_table_kernel<<<512, 256, 0, stream>>>(rc, rs);
    // 3. QKV projection: [4096,4096] x [6144,4096]^T -> qkv f32
    gemm_bt<<<dim3(QKVSZ / 128, (B_DIM * S_LEN) / 128), 256, 0, stream>>>(hb, wqb, qkv, QKVSZ, HIDDEN);
    // 4. RoPE -> Q,K bf16 (head-major layouts)
    rope_kernel<<<B_DIM * S_LEN, 256, 0, stream>>>(qkv, pos, rc, rs, Qb, Kb);
    // 5. V transpose -> Vt [B,8,128,S]
    vtrans_kernel<<<dim3(S_LEN / 64, NKV, B_DIM), 256, 0, stream>>>(qkv, Vtb);
    // 6. flash attention -> attnb [B,S,4096] bf16
    attn_kernel<<<dim3(S_LEN / 64, NHEADS, B_DIM), 256, 0, stream>>>(Qb, Kb, Vtb, attnb);
    // 7. O projection -> out f32
    gemm_bt<<<dim3(HIDDEN / 128, (B_DIM * S_LEN) / 128), 256, 0, stream>>>(attnb, wob, out, HIDDEN, QSZ);
}

// Round 3
// 950.255 us; speedup vs baseline: 1.5537x; 1.5537x over previous
//
#include <hip/hip_runtime.h>
#include <hip/hip_bf16.h>
#include <cmath>

typedef __bf16 bf16x8 __attribute__((ext_vector_type(8)));
typedef __bf16 bf16x4 __attribute__((ext_vector_type(4)));
typedef float  f32x4  __attribute__((ext_vector_type(4)));

#define AS1 __attribute__((address_space(1)))
#define AS3 __attribute__((address_space(3)))
#define GLDS16(gp, lp) __builtin_amdgcn_global_load_lds((AS1 void*)(gp), (AS3 void*)(lp), 16, 0, 0)

#define B_DIM 2
#define S_LEN 2048
#define HIDDEN 4096
#define NHEADS 32
#define NKV 8
#define HDIM 128
#define QSZ 4096
#define KVSZ 1024
#define QKVSZ 6144
#define ATT_SCALE 0.0078125f   /* 1/128 */
#define L2E 1.4426950408889634f

// ---------------- f32 -> bf16 conversion (vectorized) ----------------
__global__ __launch_bounds__(256) void conv_f32_bf16(const float* __restrict__ in,
                                                     __bf16* __restrict__ out, int n4) {
    int idx = blockIdx.x * 256 + threadIdx.x;
    if (idx < n4) {
        float4 v = ((const float4*)in)[idx];
        bf16x4 o;
        o[0] = (__bf16)v.x; o[1] = (__bf16)v.y; o[2] = (__bf16)v.z; o[3] = (__bf16)v.w;
        ((bf16x4*)out)[idx] = o;
    }
}

// ---------------- RoPE cos/sin table: [pos][i], i<64 ----------------
__global__ __launch_bounds__(256) void rope_table_kernel(float* __restrict__ ct,
                                                         float* __restrict__ st) {
    int idx = blockIdx.x * 256 + threadIdx.x;   // S_LEN*64 entries
    int p = idx >> 6, i = idx & 63;
    float inv = expf(-(float)i * (9.210340371976184f / 64.0f));
    float freq = (float)p * inv;
    float s, c;
    sincosf(freq, &s, &c);
    ct[idx] = c; st[idx] = s;
}

// ---------------- GEMM C[m,n] = sum_k A[m,k]*B[n,k]  (m97 structure) ----------------
__global__ __launch_bounds__(256) void gemm_bt(const __bf16* __restrict__ A,
                                               const __bf16* __restrict__ B,
                                               float* __restrict__ C,
                                               int N, int K) {
    __shared__ __bf16 As[128 * 32];
    __shared__ __bf16 Bs[128 * 32];
    const int tid = threadIdx.x;
    const int w = tid >> 6, l = tid & 63;
    const int l15 = l & 15, l4 = l >> 4;
    const int wr = w >> 1, wc = w & 1;
    const int m0 = blockIdx.y * 128, n0 = blockIdx.x * 128;

    f32x4 acc[4][4] = {};

    for (int kt = 0; kt < K; kt += 32) {
#pragma unroll
        for (int i = 0; i < 2; ++i) {
            int chunk = i * 256 + tid;          // 0..511
            int row = chunk >> 2;               // 0..127
            int c8 = (chunk & 3) << 3;          // 0,8,16,24
            GLDS16(A + (size_t)(m0 + row) * K + kt + c8, (char*)As + chunk * 16);
            GLDS16(B + (size_t)(n0 + row) * K + kt + c8, (char*)Bs + chunk * 16);
        }
        __syncthreads();
        bf16x8 af[4], bfr[4];
#pragma unroll
        for (int x = 0; x < 4; ++x) {
            af[x]  = *(const bf16x8*)(As + (wr * 64 + x * 16 + l15) * 32 + l4 * 8);
            bfr[x] = *(const bf16x8*)(Bs + (wc * 64 + x * 16 + l15) * 32 + l4 * 8);
        }
#pragma unroll
        for (int mi = 0; mi < 4; ++mi)
#pragma unroll
            for (int ni = 0; ni < 4; ++ni)
                acc[mi][ni] = __builtin_amdgcn_mfma_f32_16x16x32_bf16(af[mi], bfr[ni], acc[mi][ni], 0, 0, 0);
        __syncthreads();
    }
#pragma unroll
    for (int mi = 0; mi < 4; ++mi)
#pragma unroll
        for (int ni = 0; ni < 4; ++ni)
#pragma unroll
            for (int r = 0; r < 4; ++r)
                C[(size_t)(m0 + wr * 64 + mi * 16 + l4 * 4 + r) * N + n0 + wc * 64 + ni * 16 + l15] = acc[mi][ni][r];
}

// ---------------- RoPE apply: qkv f32 -> Q [B,32,S,128] bf16, K [B,8,S,128] bf16 ----------------
__global__ __launch_bounds__(256) void rope_kernel(const float* __restrict__ qkv,
                                                   const int* __restrict__ pos,
                                                   const float* __restrict__ ct,
                                                   const float* __restrict__ st,
                                                   __bf16* __restrict__ Qb,
                                                   __bf16* __restrict__ Kb) {
    const int tid = threadIdx.x;
    const int tok = blockIdx.x;                 // 0..B*S-1
    const int b = tok >> 11, s = tok & 2047;
    const int p = pos[tok];
    const float* base = qkv + (size_t)tok * QKVSZ;
    const float* cb = ct + (size_t)p * 64;
    const float* sb = st + (size_t)p * 64;
    for (int idx = tid; idx < 2560; idx += 256) {   // (32+8)*64 pairs
        int head = idx >> 6, i = idx & 63;
        float c = cb[i], sn = sb[i];
        if (head < 32) {
            float x1 = base[head * HDIM + i];
            float x2 = base[head * HDIM + 64 + i];
            size_t o = ((size_t)(b * 32 + head) * S_LEN + s) * HDIM + i;
            Qb[o]      = (__bf16)(x1 * c - x2 * sn);
            Qb[o + 64] = (__bf16)(x2 * c + x1 * sn);
        } else {
            int g = head - 32;
            float x1 = base[QSZ + g * HDIM + i];
            float x2 = base[QSZ + g * HDIM + 64 + i];
            size_t o = ((size_t)(b * 8 + g) * S_LEN + s) * HDIM + i;
            Kb[o]      = (__bf16)(x1 * c - x2 * sn);
            Kb[o + 64] = (__bf16)(x2 * c + x1 * sn);
        }
    }
}

// ---------------- V transpose: qkv f32 V-slice -> Vt [B,8,128,S] bf16 ----------------
__global__ __launch_bounds__(256) void vtrans_kernel(const float* __restrict__ qkv,
                                                     __bf16* __restrict__ Vt) {
    __shared__ __bf16 T[64][132];
    const int tid = threadIdx.x;
    const int st = blockIdx.x, g = blockIdx.y, b = blockIdx.z;
    const float* src = qkv + ((size_t)(b * S_LEN + st * 64)) * QKVSZ + (QSZ + KVSZ) + g * HDIM;
#pragma unroll
    for (int it = 0; it < 8; ++it) {
        int c = it * 256 + tid;       // 0..2047, 32 float4-chunks per row
        int row = c >> 5;
        int c4 = c & 31;
        float4 v = *(const float4*)(src + (size_t)row * QKVSZ + c4 * 4);
        bf16x4 o;
        o[0] = (__bf16)v.x; o[1] = (__bf16)v.y; o[2] = (__bf16)v.z; o[3] = (__bf16)v.w;
        *(bf16x4*)(&T[row][c4 * 4]) = o;
    }
    __syncthreads();
#pragma unroll
    for (int it = 0; it < 8; ++it) {
        int c = it * 256 + tid;       // 0..2047, 16 chunks (of 4 s-cols) per d-row
        int d = c >> 4;
        int s4 = (c & 15) * 4;
        bf16x4 o;
        o[0] = T[s4 + 0][d]; o[1] = T[s4 + 1][d]; o[2] = T[s4 + 2][d]; o[3] = T[s4 + 3][d];
        *(bf16x4*)(Vt + ((size_t)(b * 8 + g) * HDIM + d) * S_LEN + st * 64 + s4) = o;
    }
}

// ---------------- Flash attention (causal, GQA rep=4) ----------------
// Q [B,32,S,128], K [B,8,S,128], Vt [B,8,128,S] bf16 -> attn [B,S,4096] bf16
// grid (S/64, 32, B), block 256. K/V tiles staged in LDS (double-buffered,
// XOR-swizzled via pre-permuted global source), shared by all 4 waves.
__global__ __launch_bounds__(256) void attn_kernel(const __bf16* __restrict__ Q,
                                                   const __bf16* __restrict__ K,
                                                   const __bf16* __restrict__ Vt,
                                                   __bf16* __restrict__ O) {
    const int tid = threadIdx.x;
    const int w = tid >> 6, l = tid & 63;
    const int l15 = l & 15, l4 = l >> 4;
    const int qt = gridDim.x - 1 - blockIdx.x;   // reversed: long blocks first
    const int h = blockIdx.y, b = blockIdx.z;
    const int g = h >> 2;
    const int q0 = qt * 64 + w * 16;

    __shared__ __bf16 Ks[2][64 * 128];   // 2x16 KB; chunk c: row=c>>4, cc=(c&15)^(row&7)
    __shared__ __bf16 Vs[2][128 * 64];   // 2x16 KB; chunk c: row=c>>3, cc=(c&7)^(row&7)
    __shared__ __bf16 Pl[4][16][72];     // per-wave P transpose buffer

    const __bf16* Qp = Q + ((size_t)((b * 32 + h) * S_LEN + q0)) * HDIM;
    const __bf16* Kp = K + (size_t)(b * 8 + g) * S_LEN * HDIM;
    const __bf16* Vp = Vt + (size_t)(b * 8 + g) * HDIM * S_LEN;

    bf16x8 qf[4];
#pragma unroll
    for (int kk = 0; kk < 4; ++kk)
        qf[kk] = *(const bf16x8*)(Qp + (size_t)l15 * HDIM + kk * 32 + l4 * 8);

    f32x4 acc[8] = {};
    float m[4]    = {-1e30f, -1e30f, -1e30f, -1e30f};
    float lsum[4] = {0.f, 0.f, 0.f, 0.f};

#define STAGE(buf, ktile) do {                                                     \
        const __bf16* kbase = Kp + (size_t)(ktile) * 64 * HDIM;                    \
        _Pragma("unroll")                                                          \
        for (int i_ = 0; i_ < 4; ++i_) {                                           \
            int c_ = i_ * 256 + tid;            /* 1024 chunks = 64x128 bf16 */    \
            int row_ = c_ >> 4, cc_ = (c_ & 15) ^ (row_ & 7);                      \
            GLDS16(kbase + (size_t)row_ * HDIM + cc_ * 8,                          \
                   (char*)Ks[buf] + c_ * 16);                                      \
        }                                                                          \
        const __bf16* vbase = Vp + (size_t)(ktile) * 64;                           \
        _Pragma("unroll")                                                          \
        for (int i_ = 0; i_ < 4; ++i_) {                                           \
            int c_ = i_ * 256 + tid;            /* 1024 chunks = 128x64 bf16 */    \
            int row_ = c_ >> 3, cc_ = (c_ & 7) ^ (row_ & 7);                       \
            GLDS16(vbase + (size_t)row_ * S_LEN + cc_ * 8,                         \
                   (char*)Vs[buf] + c_ * 16);                                      \
        }                                                                          \
    } while (0)

    const int nkt = qt + 1;
    int cur = 0;
    STAGE(0, 0);
    __syncthreads();   // drains vmcnt(0): tile 0 ready

    for (int kt = 0; kt < nkt; ++kt) {
        if (kt + 1 < nkt) STAGE(cur ^ 1, kt + 1);   // prefetch next tile
        // ---- scores: S = Q K^T ----
        f32x4 sfr[4];
        __builtin_amdgcn_s_setprio(1);
#pragma unroll
        for (int fn = 0; fn < 4; ++fn) {
            f32x4 sa = {};
#pragma unroll
            for (int kk = 0; kk < 4; ++kk) {
                int row = fn * 16 + l15;
                int cc = (kk * 4 + l4) ^ (l15 & 7);
                bf16x8 kb = *(const bf16x8*)(Ks[cur] + row * HDIM + cc * 8);
                sa = __builtin_amdgcn_mfma_f32_16x16x32_bf16(qf[kk], kb, sa, 0, 0, 0);
            }
            sfr[fn] = sa;
        }
        __builtin_amdgcn_s_setprio(0);
        const bool last = (kt == nkt - 1);
        float pv[4][4];
#pragma unroll
        for (int r = 0; r < 4; ++r) {
            const int row = q0 + l4 * 4 + r;
            float sv[4];
            float best = -1e30f;
#pragma unroll
            for (int fn = 0; fn < 4; ++fn) {
                int col = kt * 64 + fn * 16 + l15;
                float v = sfr[fn][r] * ATT_SCALE;
                if (last && col > row) v = -1e30f;
                sv[fn] = v;
                best = fmaxf(best, v);
            }
#pragma unroll
            for (int off = 1; off < 16; off <<= 1)
                best = fmaxf(best, __shfl_xor(best, off));
            float mn = fmaxf(m[r], best);
            float alpha = exp2f((m[r] - mn) * L2E);
            m[r] = mn;
            float rs = 0.f;
#pragma unroll
            for (int fn = 0; fn < 4; ++fn) {
                float p = exp2f((sv[fn] - mn) * L2E);
                pv[fn][r] = p;
                rs += p;
            }
#pragma unroll
            for (int off = 1; off < 16; off <<= 1)
                rs += __shfl_xor(rs, off);
            lsum[r] = lsum[r] * alpha + rs;
#pragma unroll
            for (int n = 0; n < 8; ++n) acc[n][r] *= alpha;
        }
        // ---- P -> LDS (per-wave, transposed into A-fragment layout) ----
#pragma unroll
        for (int fn = 0; fn < 4; ++fn)
#pragma unroll
            for (int r = 0; r < 4; ++r)
                Pl[w][l4 * 4 + r][fn * 16 + l15] = (__bf16)pv[fn][r];
        asm volatile("s_waitcnt lgkmcnt(0)" ::: "memory");
        __builtin_amdgcn_sched_barrier(0);
        // ---- PV ----
        __builtin_amdgcn_s_setprio(1);
#pragma unroll
        for (int kk = 0; kk < 2; ++kk) {
            bf16x8 pa = *(const bf16x8*)(&Pl[w][l15][kk * 32 + l4 * 8]);
#pragma unroll
            for (int n = 0; n < 8; ++n) {
                int row = n * 16 + l15;
                int cc = (kk * 4 + l4) ^ (l15 & 7);
                bf16x8 vb = *(const bf16x8*)(Vs[cur] + row * 64 + cc * 8);
                acc[n] = __builtin_amdgcn_mfma_f32_16x16x32_bf16(pa, vb, acc[n], 0, 0, 0);
            }
        }
        __builtin_amdgcn_s_setprio(0);
        __syncthreads();   // drains vmcnt(0) (next tile ready) + lgkmcnt
        cur ^= 1;
    }
#undef STAGE
    // ---- epilogue: attn[b, row, h*128 + d] ----
#pragma unroll
    for (int n = 0; n < 8; ++n)
#pragma unroll
        for (int r = 0; r < 4; ++r) {
            int row = q0 + l4 * 4 + r;
            O[((size_t)(b * S_LEN) + row) * QSZ + h * HDIM + n * 16 + l15] = (__bf16)(acc[n][r] / lsum[r]);
        }
}

extern "C" void kernel_launch(void* const* d_in, const int* in_sizes, int n_in,
                              void* d_out, int out_size, void* d_ws, size_t ws_size,
                              hipStream_t stream) {
    const int*   pos    = (const int*)d_in[0];
    const float* hidden = (const float*)d_in[1];
    const float* wqkv   = (const float*)d_in[2];
    const float* wo     = (const float*)d_in[3];
    float* out = (float*)d_out;

    // workspace carve
    __bf16* hb    = (__bf16*)d_ws;                     // 16,777,216 elems
    __bf16* wqb   = hb  + 16777216;                    // 25,165,824
    __bf16* wob   = wqb + 25165824;                    // 16,777,216
    float*  qkv   = (float*)(wob + 16777216);          // 25,165,824 f32
    __bf16* Qb    = (__bf16*)(qkv + 25165824);         // 16,777,216
    __bf16* Kb    = Qb  + 16777216;                    // 4,194,304
    __bf16* Vtb   = Kb  + 4194304;                     // 4,194,304
    __bf16* attnb = Vtb + 4194304;                     // 16,777,216
    float*  rc    = (float*)(attnb + 16777216);        // 131,072
    float*  rs    = rc + 131072;                       // 131,072

    conv_f32_bf16<<<16384, 256, 0, stream>>>(hidden, hb, 4194304);
    conv_f32_bf16<<<24576, 256, 0, stream>>>(wqkv, wqb, 6291456);
    conv_f32_bf16<<<16384, 256, 0, stream>>>(wo, wob, 4194304);
    rope_table_kernel<<<512, 256, 0, stream>>>(rc, rs);
    gemm_bt<<<dim3(QKVSZ / 128, (B_DIM * S_LEN) / 128), 256, 0, stream>>>(hb, wqb, qkv, QKVSZ, HIDDEN);
    rope_kernel<<<B_DIM * S_LEN, 256, 0, stream>>>(qkv, pos, rc, rs, Qb, Kb);
    vtrans_kernel<<<dim3(S_LEN / 64, NKV, B_DIM), 256, 0, stream>>>(qkv, Vtb);
    attn_kernel<<<dim3(S_LEN / 64, NHEADS, B_DIM), 256, 0, stream>>>(Qb, Kb, Vtb, attnb);
    gemm_bt<<<dim3(HIDDEN / 128, (B_DIM * S_LEN) / 128), 256, 0, stream>>>(attnb, wob, out, HIDDEN, QSZ);
}

// Round 4
// 849.395 us; speedup vs baseline: 1.7382x; 1.1187x over previous
//
#include <hip/hip_runtime.h>
#include <hip/hip_bf16.h>
#include <cmath>

typedef __bf16 bf16x8 __attribute__((ext_vector_type(8)));
typedef __bf16 bf16x4 __attribute__((ext_vector_type(4)));
typedef float  f32x4  __attribute__((ext_vector_type(4)));

#define AS1 __attribute__((address_space(1)))
#define AS3 __attribute__((address_space(3)))
#define GLDS16(gp, lp) __builtin_amdgcn_global_load_lds((AS1 void*)(gp), (AS3 void*)(lp), 16, 0, 0)

#define B_DIM 2
#define S_LEN 2048
#define HIDDEN 4096
#define NHEADS 32
#define NKV 8
#define HDIM 128
#define QSZ 4096
#define KVSZ 1024
#define QKVSZ 6144
#define ATT_SCALE 0.0078125f   /* 1/128, folded into Qb at RoPE time */
#define L2E 1.4426950408889634f

// ---------------- f32 -> bf16 conversion (vectorized) ----------------
__global__ __launch_bounds__(256) void conv_f32_bf16(const float* __restrict__ in,
                                                     __bf16* __restrict__ out, int n4) {
    int idx = blockIdx.x * 256 + threadIdx.x;
    if (idx < n4) {
        float4 v = ((const float4*)in)[idx];
        bf16x4 o;
        o[0] = (__bf16)v.x; o[1] = (__bf16)v.y; o[2] = (__bf16)v.z; o[3] = (__bf16)v.w;
        ((bf16x4*)out)[idx] = o;
    }
}

// ---------------- RoPE cos/sin table: [pos][i], i<64 ----------------
__global__ __launch_bounds__(256) void rope_table_kernel(float* __restrict__ ct,
                                                         float* __restrict__ st) {
    int idx = blockIdx.x * 256 + threadIdx.x;   // S_LEN*64 entries
    int p = idx >> 6, i = idx & 63;
    float inv = expf(-(float)i * (9.210340371976184f / 64.0f));
    float freq = (float)p * inv;
    float s, c;
    sincosf(freq, &s, &c);
    ct[idx] = c; st[idx] = s;
}

// ---------------- GEMM C[m,n] = sum_k A[m,k]*B[n,k]  (m97 structure) ----------------
__global__ __launch_bounds__(256) void gemm_bt(const __bf16* __restrict__ A,
                                               const __bf16* __restrict__ B,
                                               float* __restrict__ C,
                                               int N, int K) {
    __shared__ __bf16 As[128 * 32];
    __shared__ __bf16 Bs[128 * 32];
    const int tid = threadIdx.x;
    const int w = tid >> 6, l = tid & 63;
    const int l15 = l & 15, l4 = l >> 4;
    const int wr = w >> 1, wc = w & 1;
    const int m0 = blockIdx.y * 128, n0 = blockIdx.x * 128;

    f32x4 acc[4][4] = {};

    for (int kt = 0; kt < K; kt += 32) {
#pragma unroll
        for (int i = 0; i < 2; ++i) {
            int chunk = i * 256 + tid;          // 0..511
            int row = chunk >> 2;               // 0..127
            int c8 = (chunk & 3) << 3;          // 0,8,16,24
            GLDS16(A + (size_t)(m0 + row) * K + kt + c8, (char*)As + chunk * 16);
            GLDS16(B + (size_t)(n0 + row) * K + kt + c8, (char*)Bs + chunk * 16);
        }
        __syncthreads();
        bf16x8 af[4], bfr[4];
#pragma unroll
        for (int x = 0; x < 4; ++x) {
            af[x]  = *(const bf16x8*)(As + (wr * 64 + x * 16 + l15) * 32 + l4 * 8);
            bfr[x] = *(const bf16x8*)(Bs + (wc * 64 + x * 16 + l15) * 32 + l4 * 8);
        }
#pragma unroll
        for (int mi = 0; mi < 4; ++mi)
#pragma unroll
            for (int ni = 0; ni < 4; ++ni)
                acc[mi][ni] = __builtin_amdgcn_mfma_f32_16x16x32_bf16(af[mi], bfr[ni], acc[mi][ni], 0, 0, 0);
        __syncthreads();
    }
#pragma unroll
    for (int mi = 0; mi < 4; ++mi)
#pragma unroll
        for (int ni = 0; ni < 4; ++ni)
#pragma unroll
            for (int r = 0; r < 4; ++r)
                C[(size_t)(m0 + wr * 64 + mi * 16 + l4 * 4 + r) * N + n0 + wc * 64 + ni * 16 + l15] = acc[mi][ni][r];
}

// ---------------- RoPE apply: qkv f32 -> Q (pre-scaled) [B,32,S,128], K [B,8,S,128] bf16 ----------------
__global__ __launch_bounds__(256) void rope_kernel(const float* __restrict__ qkv,
                                                   const int* __restrict__ pos,
                                                   const float* __restrict__ ct,
                                                   const float* __restrict__ st,
                                                   __bf16* __restrict__ Qb,
                                                   __bf16* __restrict__ Kb) {
    const int tid = threadIdx.x;
    const int tok = blockIdx.x;                 // 0..B*S-1
    const int b = tok >> 11, s = tok & 2047;
    const int p = pos[tok];
    const float* base = qkv + (size_t)tok * QKVSZ;
    const float* cb = ct + (size_t)p * 64;
    const float* sb = st + (size_t)p * 64;
    for (int idx = tid; idx < 2560; idx += 256) {   // (32+8)*64 pairs
        int head = idx >> 6, i = idx & 63;
        float c = cb[i], sn = sb[i];
        if (head < 32) {
            float x1 = base[head * HDIM + i];
            float x2 = base[head * HDIM + 64 + i];
            size_t o = ((size_t)(b * 32 + head) * S_LEN + s) * HDIM + i;
            Qb[o]      = (__bf16)((x1 * c - x2 * sn) * ATT_SCALE);
            Qb[o + 64] = (__bf16)((x2 * c + x1 * sn) * ATT_SCALE);
        } else {
            int g = head - 32;
            float x1 = base[QSZ + g * HDIM + i];
            float x2 = base[QSZ + g * HDIM + 64 + i];
            size_t o = ((size_t)(b * 8 + g) * S_LEN + s) * HDIM + i;
            Kb[o]      = (__bf16)(x1 * c - x2 * sn);
            Kb[o + 64] = (__bf16)(x2 * c + x1 * sn);
        }
    }
}

// ---------------- V transpose: qkv f32 V-slice -> Vt [B,8,128,S] bf16 ----------------
__global__ __launch_bounds__(256) void vtrans_kernel(const float* __restrict__ qkv,
                                                     __bf16* __restrict__ Vt) {
    __shared__ __bf16 T[64][132];
    const int tid = threadIdx.x;
    const int st = blockIdx.x, g = blockIdx.y, b = blockIdx.z;
    const float* src = qkv + ((size_t)(b * S_LEN + st * 64)) * QKVSZ + (QSZ + KVSZ) + g * HDIM;
#pragma unroll
    for (int it = 0; it < 8; ++it) {
        int c = it * 256 + tid;       // 0..2047, 32 float4-chunks per row
        int row = c >> 5;
        int c4 = c & 31;
        float4 v = *(const float4*)(src + (size_t)row * QKVSZ + c4 * 4);
        bf16x4 o;
        o[0] = (__bf16)v.x; o[1] = (__bf16)v.y; o[2] = (__bf16)v.z; o[3] = (__bf16)v.w;
        *(bf16x4*)(&T[row][c4 * 4]) = o;
    }
    __syncthreads();
#pragma unroll
    for (int it = 0; it < 8; ++it) {
        int c = it * 256 + tid;       // 0..2047, 16 chunks (of 4 s-cols) per d-row
        int d = c >> 4;
        int s4 = (c & 15) * 4;
        bf16x4 o;
        o[0] = T[s4 + 0][d]; o[1] = T[s4 + 1][d]; o[2] = T[s4 + 2][d]; o[3] = T[s4 + 3][d];
        *(bf16x4*)(Vt + ((size_t)(b * 8 + g) * HDIM + d) * S_LEN + st * 64 + s4) = o;
    }
}

// ---------------- Flash attention (causal, GQA rep=4) ----------------
// Swapped QK^T (mfma(K,Q)) -> S[k][q], softmax mostly lane-local (T12-style),
// defer-max rescale (T13). K/V double-buffered in swizzled LDS.
__global__ __launch_bounds__(256) void attn_kernel(const __bf16* __restrict__ Q,
                                                   const __bf16* __restrict__ K,
                                                   const __bf16* __restrict__ Vt,
                                                   __bf16* __restrict__ O) {
    const int tid = threadIdx.x;
    const int w = tid >> 6, l = tid & 63;
    const int l15 = l & 15, l4 = l >> 4;
    const int qt = gridDim.x - 1 - blockIdx.x;   // reversed: long blocks first
    const int h = blockIdx.y, b = blockIdx.z;
    const int g = h >> 2;
    const int q0 = qt * 64 + w * 16;

    __shared__ __bf16 Ks[2][64 * 128];   // 2x16 KB; chunk c: row=c>>4, cc=(c&15)^(row&7)
    __shared__ __bf16 Vs[2][128 * 64];   // 2x16 KB; chunk c: row=c>>3, cc=(c&7)^(row&7)
    __shared__ __bf16 Pl[4][16][72];     // per-wave P buffer: [q][k]

    const __bf16* Qp = Q + ((size_t)((b * 32 + h) * S_LEN + q0)) * HDIM;
    const __bf16* Kp = K + (size_t)(b * 8 + g) * S_LEN * HDIM;
    const __bf16* Vp = Vt + (size_t)(b * 8 + g) * HDIM * S_LEN;

    bf16x8 qf[4];
#pragma unroll
    for (int kk = 0; kk < 4; ++kk)
        qf[kk] = *(const bf16x8*)(Qp + (size_t)l15 * HDIM + kk * 32 + l4 * 8);

    f32x4 acc[8] = {};
    float m = -1e30f;     // running max for q = q0 + l15 (replicated over l4)
    float lsum = 0.f;     // running denom for q = q0 + l15
    const int qrow = q0 + l15;

#define STAGE(buf, ktile) do {                                                     \
        const __bf16* kbase = Kp + (size_t)(ktile) * 64 * HDIM;                    \
        _Pragma("unroll")                                                          \
        for (int i_ = 0; i_ < 4; ++i_) {                                           \
            int c_ = i_ * 256 + tid;            /* 1024 chunks = 64x128 bf16 */    \
            int row_ = c_ >> 4, cc_ = (c_ & 15) ^ (row_ & 7);                      \
            GLDS16(kbase + (size_t)row_ * HDIM + cc_ * 8,                          \
                   (char*)Ks[buf] + c_ * 16);                                      \
        }                                                                          \
        const __bf16* vbase = Vp + (size_t)(ktile) * 64;                           \
        _Pragma("unroll")                                                          \
        for (int i_ = 0; i_ < 4; ++i_) {                                           \
            int c_ = i_ * 256 + tid;            /* 1024 chunks = 128x64 bf16 */    \
            int row_ = c_ >> 3, cc_ = (c_ & 7) ^ (row_ & 7);                       \
            GLDS16(vbase + (size_t)row_ * S_LEN + cc_ * 8,                         \
                   (char*)Vs[buf] + c_ * 16);                                      \
        }                                                                          \
    } while (0)

    const int nkt = qt + 1;
    int cur = 0;
    STAGE(0, 0);
    __syncthreads();   // drains vmcnt(0): tile 0 ready

    for (int kt = 0; kt < nkt; ++kt) {
        if (kt + 1 < nkt) STAGE(cur ^ 1, kt + 1);   // prefetch next tile
        // ---- scores (swapped): S[k = fn*16 + l4*4 + r][q = q0 + l15] ----
        f32x4 sfr[4];
        __builtin_amdgcn_s_setprio(1);
#pragma unroll
        for (int fn = 0; fn < 4; ++fn) {
            f32x4 sa = {};
#pragma unroll
            for (int kk = 0; kk < 4; ++kk) {
                int row = fn * 16 + l15;
                int cc = (kk * 4 + l4) ^ (l15 & 7);
                bf16x8 kb = *(const bf16x8*)(Ks[cur] + row * HDIM + cc * 8);
                sa = __builtin_amdgcn_mfma_f32_16x16x32_bf16(kb, qf[kk], sa, 0, 0, 0);
            }
            sfr[fn] = sa;
        }
        __builtin_amdgcn_s_setprio(0);
        // ---- softmax (mostly lane-local; reduce only over l4 dim) ----
        const bool last = (kt == nkt - 1);
        float sv[16];
        float pmax = -1e30f;
#pragma unroll
        for (int fn = 0; fn < 4; ++fn)
#pragma unroll
            for (int r = 0; r < 4; ++r) {
                float v = sfr[fn][r];
                if (last) {
                    int kcol = kt * 64 + fn * 16 + l4 * 4 + r;
                    if (kcol > qrow) v = -1e30f;
                }
                sv[fn * 4 + r] = v;
                pmax = fmaxf(pmax, v);
            }
        pmax = fmaxf(pmax, __shfl_xor(pmax, 16));
        pmax = fmaxf(pmax, __shfl_xor(pmax, 32));
        if (!__all(pmax - m <= 8.0f)) {          // defer-max: rescale rarely
            float mn = fmaxf(m, pmax);
            float alpha = exp2f((m - mn) * L2E);
            m = mn;
            lsum *= alpha;
#pragma unroll
            for (int r = 0; r < 4; ++r) {
                float ar = __shfl(alpha, l4 * 4 + r, 16);
#pragma unroll
                for (int n = 0; n < 8; ++n) acc[n][r] *= ar;
            }
        }
        float rs = 0.f;
#pragma unroll
        for (int fn = 0; fn < 4; ++fn) {
            bf16x4 pk;
#pragma unroll
            for (int r = 0; r < 4; ++r) {
                float p = exp2f((sv[fn * 4 + r] - m) * L2E);
                rs += p;
                pk[r] = (__bf16)p;
            }
            *(bf16x4*)(&Pl[w][l15][fn * 16 + l4 * 4]) = pk;   // ds_write_b64
        }
        rs += __shfl_xor(rs, 16);
        rs += __shfl_xor(rs, 32);
        lsum += rs;
        asm volatile("s_waitcnt lgkmcnt(0)" ::: "memory");
        __builtin_amdgcn_sched_barrier(0);
        // ---- PV ----
        __builtin_amdgcn_s_setprio(1);
#pragma unroll
        for (int kk = 0; kk < 2; ++kk) {
            bf16x8 pa = *(const bf16x8*)(&Pl[w][l15][kk * 32 + l4 * 8]);
#pragma unroll
            for (int n = 0; n < 8; ++n) {
                int row = n * 16 + l15;
                int cc = (kk * 4 + l4) ^ (l15 & 7);
                bf16x8 vb = *(const bf16x8*)(Vs[cur] + row * 64 + cc * 8);
                acc[n] = __builtin_amdgcn_mfma_f32_16x16x32_bf16(pa, vb, acc[n], 0, 0, 0);
            }
        }
        __builtin_amdgcn_s_setprio(0);
        __syncthreads();   // drains vmcnt(0) (next tile ready) + lgkmcnt
        cur ^= 1;
    }
#undef STAGE
    // ---- epilogue: attn[b, row, h*128 + d] ----
#pragma unroll
    for (int r = 0; r < 4; ++r) {
        float inv = 1.0f / __shfl(lsum, l4 * 4 + r, 16);
        int row = q0 + l4 * 4 + r;
#pragma unroll
        for (int n = 0; n < 8; ++n)
            O[((size_t)(b * S_LEN) + row) * QSZ + h * HDIM + n * 16 + l15] = (__bf16)(acc[n][r] * inv);
    }
}

extern "C" void kernel_launch(void* const* d_in, const int* in_sizes, int n_in,
                              void* d_out, int out_size, void* d_ws, size_t ws_size,
                              hipStream_t stream) {
    const int*   pos    = (const int*)d_in[0];
    const float* hidden = (const float*)d_in[1];
    const float* wqkv   = (const float*)d_in[2];
    const float* wo     = (const float*)d_in[3];
    float* out = (float*)d_out;

    // workspace carve
    __bf16* hb    = (__bf16*)d_ws;                     // 16,777,216 elems
    __bf16* wqb   = hb  + 16777216;                    // 25,165,824
    __bf16* wob   = wqb + 25165824;                    // 16,777,216
    float*  qkv   = (float*)(wob + 16777216);          // 25,165,824 f32
    __bf16* Qb    = (__bf16*)(qkv + 25165824);         // 16,777,216
    __bf16* Kb    = Qb  + 16777216;                    // 4,194,304
    __bf16* Vtb   = Kb  + 4194304;                     // 4,194,304
    __bf16* attnb = Vtb + 4194304;                     // 16,777,216
    float*  rc    = (float*)(attnb + 16777216);        // 131,072
    float*  rs    = rc + 131072;                       // 131,072

    conv_f32_bf16<<<16384, 256, 0, stream>>>(hidden, hb, 4194304);
    conv_f32_bf16<<<24576, 256, 0, stream>>>(wqkv, wqb, 6291456);
    conv_f32_bf16<<<16384, 256, 0, stream>>>(wo, wob, 4194304);
    rope_table_kernel<<<512, 256, 0, stream>>>(rc, rs);
    gemm_bt<<<dim3(QKVSZ / 128, (B_DIM * S_LEN) / 128), 256, 0, stream>>>(hb, wqb, qkv, QKVSZ, HIDDEN);
    rope_kernel<<<B_DIM * S_LEN, 256, 0, stream>>>(qkv, pos, rc, rs, Qb, Kb);
    vtrans_kernel<<<dim3(S_LEN / 64, NKV, B_DIM), 256, 0, stream>>>(qkv, Vtb);
    attn_kernel<<<dim3(S_LEN / 64, NHEADS, B_DIM), 256, 0, stream>>>(Qb, Kb, Vtb, attnb);
    gemm_bt<<<dim3(HIDDEN / 128, (B_DIM * S_LEN) / 128), 256, 0, stream>>>(attnb, wob, out, HIDDEN, QSZ);
}

// Round 5
// 714.126 us; speedup vs baseline: 2.0674x; 1.1894x over previous
//
#include <hip/hip_runtime.h>
#include <hip/hip_bf16.h>
#include <cmath>

typedef __bf16 bf16x8 __attribute__((ext_vector_type(8)));
typedef __bf16 bf16x4 __attribute__((ext_vector_type(4)));
typedef float  f32x4  __attribute__((ext_vector_type(4)));

#define AS1 __attribute__((address_space(1)))
#define AS3 __attribute__((address_space(3)))
#define GLDS16(gp, lp) __builtin_amdgcn_global_load_lds((AS1 void*)(gp), (AS3 void*)(lp), 16, 0, 0)

#define B_DIM 2
#define S_LEN 2048
#define HIDDEN 4096
#define NHEADS 32
#define NKV 8
#define HDIM 128
#define QSZ 4096
#define KVSZ 1024
#define QKVSZ 6144
#define GK 4096                /* K of both GEMMs */
#define ATT_SCALE 0.0078125f   /* 1/128, folded into Qb at RoPE time */
#define L2E 1.4426950408889634f

// ---------------- f32 -> bf16 conversion (vectorized) ----------------
__global__ __launch_bounds__(256) void conv_f32_bf16(const float* __restrict__ in,
                                                     __bf16* __restrict__ out, int n4) {
    int idx = blockIdx.x * 256 + threadIdx.x;
    if (idx < n4) {
        float4 v = ((const float4*)in)[idx];
        bf16x4 o;
        o[0] = (__bf16)v.x; o[1] = (__bf16)v.y; o[2] = (__bf16)v.z; o[3] = (__bf16)v.w;
        ((bf16x4*)out)[idx] = o;
    }
}

// ---------------- RoPE cos/sin table: [pos][i], i<64 ----------------
__global__ __launch_bounds__(256) void rope_table_kernel(float* __restrict__ ct,
                                                         float* __restrict__ st) {
    int idx = blockIdx.x * 256 + threadIdx.x;   // S_LEN*64 entries
    int p = idx >> 6, i = idx & 63;
    float inv = expf(-(float)i * (9.210340371976184f / 64.0f));
    float freq = (float)p * inv;
    float s, c;
    sincosf(freq, &s, &c);
    ct[idx] = c; st[idx] = s;
}

// ---------------- 256x256 8-phase GEMM: C[m,n] = sum_k A[m,k]*B[n,k] ----------------
// A [M,GK], B [N,GK] bf16 row-major; C [M,N] f32. M,N mult of 256; GK=4096.
// 512 thr = 8 waves (2Mx4N); per-wave out 128x64. BK=64, double-buffered 128KB LDS.
// 4 phases per K-tile, counted vmcnt(4) per tile boundary, raw barriers.
// LDS chunk-XOR swizzle: LDS 16B-chunk j of row r holds global chunk j^(r&7).
__global__ __launch_bounds__(512, 2) void gemm256(const __bf16* __restrict__ A,
                                                  const __bf16* __restrict__ B,
                                                  float* __restrict__ C,
                                                  int N) {
    __shared__ __bf16 Asm[2 * 16384 + 2 * 16384];   // A: 2 slots x 32KB, B: 2 slots x 32KB
    char* Bbase = (char*)Asm + 65536;

    const int tid = threadIdx.x;
    const int w = tid >> 6, l = tid & 63;
    const int l15 = l & 15, l4 = l >> 4;
    const int wr = w >> 2, wc = w & 3;

    // XCD-bijective swizzle (nwg % 8 == 0 for both call sites)
    const int nwg = gridDim.x * gridDim.y;
    const int orig = blockIdx.y * gridDim.x + blockIdx.x;
    const int swz = (orig & 7) * (nwg >> 3) + (orig >> 3);
    const int bx = swz % gridDim.x, by = swz / gridDim.x;
    const int m0 = by * 256, n0 = bx * 256;

    const __bf16* Ag = A + (size_t)m0 * GK;
    const __bf16* Bg = B + (size_t)n0 * GK;

    // --- staging units (per thread -> one GLDS16 each) ---
    // A quarter q: tile rows q*64..q*64+63 (1 load). B stripe-set s: rows with
    // ((r>>5)&1)==s, i.e. 4 stripes of 32 rows (2 loads).
#define STAGE_AQ(q, tile) do {                                                  \
        int c_ = (q) * 512 + tid;                                               \
        int r_ = c_ >> 3;                                                       \
        int jg_ = (tid & 7) ^ (r_ & 7);                                         \
        GLDS16(Ag + (size_t)r_ * GK + (tile) * 64 + jg_ * 8,                    \
               (char*)Asm + ((tile) & 1) * 32768 + c_ * 16);                    \
    } while (0)
#define STAGE_BS(s, tile) do {                                                  \
        _Pragma("unroll")                                                       \
        for (int i_ = 0; i_ < 2; ++i_) {                                        \
            int v_ = i_ * 512 + tid;                                            \
            int r_ = (v_ >> 8) * 64 + (s) * 32 + ((v_ >> 3) & 31);              \
            int jg_ = (v_ & 7) ^ (r_ & 7);                                      \
            int c_ = r_ * 8 + (v_ & 7);                                         \
            GLDS16(Bg + (size_t)r_ * GK + (tile) * 64 + jg_ * 8,                \
                   Bbase + ((tile) & 1) * 32768 + c_ * 16);                     \
        }                                                                       \
    } while (0)

    f32x4 acc[8][4] = {};

    const int T = GK / 64;   // 64 K-tiles
    // ---- prologue: tile 0 fully + Aq0(1), Aq2(1), S0(1); leave those 4 in flight ----
    STAGE_AQ(0, 0); STAGE_AQ(1, 0); STAGE_AQ(2, 0); STAGE_AQ(3, 0);
    STAGE_BS(0, 0); STAGE_BS(1, 0);
    STAGE_AQ(0, 1); STAGE_AQ(2, 1); STAGE_BS(0, 1);
    asm volatile("s_waitcnt vmcnt(4)" ::: "memory");
    __builtin_amdgcn_s_barrier();

    // phase = (MH, NH): computes acc[MH*4..+3][NH*2..+1] over full BK=64.
    // A quarter deaths: mh0 quarters after ph1, mh1 after ph3.
    // B stripe-set deaths: S0 after ph2, S1 after ph3.
#define PHASE(MH, NH, STAGES, WAITS)                                            \
    {                                                                           \
        bf16x8 af[4][2], bfr[2][2];                                             \
        _Pragma("unroll")                                                       \
        for (int m2 = 0; m2 < 4; ++m2) {                                        \
            int row = wr * 128 + ((MH) * 4 + m2) * 16 + l15;                    \
            _Pragma("unroll")                                                   \
            for (int kk = 0; kk < 2; ++kk) {                                    \
                int j = (kk * 4 + l4) ^ (row & 7);                              \
                af[m2][kk] = *(const bf16x8*)(Als + row * 64 + j * 8);          \
            }                                                                   \
        }                                                                       \
        _Pragma("unroll")                                                       \
        for (int n2 = 0; n2 < 2; ++n2) {                                        \
            int row = wc * 64 + ((NH) * 2 + n2) * 16 + l15;                     \
            _Pragma("unroll")                                                   \
            for (int kk = 0; kk < 2; ++kk) {                                    \
                int j = (kk * 4 + l4) ^ (row & 7);                              \
                bfr[n2][kk] = *(const bf16x8*)(Bls + row * 64 + j * 8);         \
            }                                                                   \
        }                                                                       \
        STAGES;                                                                 \
        __builtin_amdgcn_sched_barrier(0);                                      \
        __builtin_amdgcn_s_barrier();                                           \
        asm volatile("s_waitcnt lgkmcnt(0)" ::: "memory");                      \
        __builtin_amdgcn_sched_barrier(0);                                      \
        __builtin_amdgcn_s_setprio(1);                                          \
        _Pragma("unroll")                                                       \
        for (int m2 = 0; m2 < 4; ++m2)                                          \
            _Pragma("unroll")                                                   \
            for (int n2 = 0; n2 < 2; ++n2)                                      \
                _Pragma("unroll")                                               \
                for (int kk = 0; kk < 2; ++kk)                                  \
                    acc[(MH) * 4 + m2][(NH) * 2 + n2] =                         \
                        __builtin_amdgcn_mfma_f32_16x16x32_bf16(                \
                            af[m2][kk], bfr[n2][kk],                            \
                            acc[(MH) * 4 + m2][(NH) * 2 + n2], 0, 0, 0);        \
        __builtin_amdgcn_s_setprio(0);                                          \
        WAITS;                                                                  \
        __builtin_amdgcn_sched_barrier(0);                                      \
        __builtin_amdgcn_s_barrier();                                           \
    }

    for (int t = 0; t < T; ++t) {
        const int slot = t & 1;
        const __bf16* Als = Asm + slot * 16384;
        const __bf16* Bls = (__bf16*)Bbase + slot * 16384;
        // ph0 (mh0,nh0): stage Aq1(t+1), Aq3(t+1)  [regions died at t-1 ph3]
        PHASE(0, 0,
              { if (t + 1 < T) { STAGE_AQ(1, t + 1); STAGE_AQ(3, t + 1); } },
              {});
        // ph1 (mh0,nh1): stage S1(t+1)             [died t-1 ph3]
        PHASE(0, 1,
              { if (t + 1 < T) { STAGE_BS(1, t + 1); } },
              {});
        // ph2 (mh1,nh0): stage Aq0(t+2), Aq2(t+2)  [died this tile ph1]
        PHASE(1, 0,
              { if (t + 2 < T) { STAGE_AQ(0, t + 2); STAGE_AQ(2, t + 2); } },
              {});
        // ph3 (mh1,nh1): stage S0(t+2)             [died this tile ph2]
        // boundary wait: force all of tile t+1; newest-4 in flight = Aq0/Aq2/S0(t+2)
        PHASE(1, 1,
              { if (t + 2 < T) { STAGE_BS(0, t + 2); } },
              {
                  if (t + 2 < T)      { asm volatile("s_waitcnt vmcnt(4)" ::: "memory"); }
                  else if (t + 1 < T) { asm volatile("s_waitcnt vmcnt(0)" ::: "memory"); }
              });
    }
#undef PHASE
#undef STAGE_AQ
#undef STAGE_BS

    // ---- epilogue ----
#pragma unroll
    for (int mi = 0; mi < 8; ++mi)
#pragma unroll
        for (int ni = 0; ni < 4; ++ni)
#pragma unroll
            for (int r = 0; r < 4; ++r)
                C[(size_t)(m0 + wr * 128 + mi * 16 + l4 * 4 + r) * N
                  + n0 + wc * 64 + ni * 16 + l15] = acc[mi][ni][r];
}

// ---------------- RoPE apply: qkv f32 -> Q (pre-scaled) [B,32,S,128], K [B,8,S,128] bf16 ----------------
__global__ __launch_bounds__(256) void rope_kernel(const float* __restrict__ qkv,
                                                   const int* __restrict__ pos,
                                                   const float* __restrict__ ct,
                                                   const float* __restrict__ st,
                                                   __bf16* __restrict__ Qb,
                                                   __bf16* __restrict__ Kb) {
    const int tid = threadIdx.x;
    const int tok = blockIdx.x;                 // 0..B*S-1
    const int b = tok >> 11, s = tok & 2047;
    const int p = pos[tok];
    const float* base = qkv + (size_t)tok * QKVSZ;
    const float* cb = ct + (size_t)p * 64;
    const float* sb = st + (size_t)p * 64;
    for (int idx = tid; idx < 2560; idx += 256) {   // (32+8)*64 pairs
        int head = idx >> 6, i = idx & 63;
        float c = cb[i], sn = sb[i];
        if (head < 32) {
            float x1 = base[head * HDIM + i];
            float x2 = base[head * HDIM + 64 + i];
            size_t o = ((size_t)(b * 32 + head) * S_LEN + s) * HDIM + i;
            Qb[o]      = (__bf16)((x1 * c - x2 * sn) * ATT_SCALE);
            Qb[o + 64] = (__bf16)((x2 * c + x1 * sn) * ATT_SCALE);
        } else {
            int g = head - 32;
            float x1 = base[QSZ + g * HDIM + i];
            float x2 = base[QSZ + g * HDIM + 64 + i];
            size_t o = ((size_t)(b * 8 + g) * S_LEN + s) * HDIM + i;
            Kb[o]      = (__bf16)(x1 * c - x2 * sn);
            Kb[o + 64] = (__bf16)(x2 * c + x1 * sn);
        }
    }
}

// ---------------- V transpose: qkv f32 V-slice -> Vt [B,8,128,S] bf16 ----------------
__global__ __launch_bounds__(256) void vtrans_kernel(const float* __restrict__ qkv,
                                                     __bf16* __restrict__ Vt) {
    __shared__ __bf16 T[64][132];
    const int tid = threadIdx.x;
    const int st = blockIdx.x, g = blockIdx.y, b = blockIdx.z;
    const float* src = qkv + ((size_t)(b * S_LEN + st * 64)) * QKVSZ + (QSZ + KVSZ) + g * HDIM;
#pragma unroll
    for (int it = 0; it < 8; ++it) {
        int c = it * 256 + tid;       // 0..2047, 32 float4-chunks per row
        int row = c >> 5;
        int c4 = c & 31;
        float4 v = *(const float4*)(src + (size_t)row * QKVSZ + c4 * 4);
        bf16x4 o;
        o[0] = (__bf16)v.x; o[1] = (__bf16)v.y; o[2] = (__bf16)v.z; o[3] = (__bf16)v.w;
        *(bf16x4*)(&T[row][c4 * 4]) = o;
    }
    __syncthreads();
#pragma unroll
    for (int it = 0; it < 8; ++it) {
        int c = it * 256 + tid;       // 0..2047, 16 chunks (of 4 s-cols) per d-row
        int d = c >> 4;
        int s4 = (c & 15) * 4;
        bf16x4 o;
        o[0] = T[s4 + 0][d]; o[1] = T[s4 + 1][d]; o[2] = T[s4 + 2][d]; o[3] = T[s4 + 3][d];
        *(bf16x4*)(Vt + ((size_t)(b * 8 + g) * HDIM + d) * S_LEN + st * 64 + s4) = o;
    }
}

// ---------------- Flash attention (causal, GQA rep=4) ----------------
// Swapped QK^T (mfma(K,Q)) -> S[k][q], softmax mostly lane-local (T12-style),
// defer-max rescale (T13). K/V double-buffered in swizzled LDS.
__global__ __launch_bounds__(256) void attn_kernel(const __bf16* __restrict__ Q,
                                                   const __bf16* __restrict__ K,
                                                   const __bf16* __restrict__ Vt,
                                                   __bf16* __restrict__ O) {
    const int tid = threadIdx.x;
    const int w = tid >> 6, l = tid & 63;
    const int l15 = l & 15, l4 = l >> 4;
    const int qt = gridDim.x - 1 - blockIdx.x;   // reversed: long blocks first
    const int h = blockIdx.y, b = blockIdx.z;
    const int g = h >> 2;
    const int q0 = qt * 64 + w * 16;

    __shared__ __bf16 Ks[2][64 * 128];   // 2x16 KB; chunk c: row=c>>4, cc=(c&15)^(row&7)
    __shared__ __bf16 Vs[2][128 * 64];   // 2x16 KB; chunk c: row=c>>3, cc=(c&7)^(row&7)
    __shared__ __bf16 Pl[4][16][72];     // per-wave P buffer: [q][k]

    const __bf16* Qp = Q + ((size_t)((b * 32 + h) * S_LEN + q0)) * HDIM;
    const __bf16* Kp = K + (size_t)(b * 8 + g) * S_LEN * HDIM;
    const __bf16* Vp = Vt + (size_t)(b * 8 + g) * HDIM * S_LEN;

    bf16x8 qf[4];
#pragma unroll
    for (int kk = 0; kk < 4; ++kk)
        qf[kk] = *(const bf16x8*)(Qp + (size_t)l15 * HDIM + kk * 32 + l4 * 8);

    f32x4 acc[8] = {};
    float m = -1e30f;     // running max for q = q0 + l15 (replicated over l4)
    float lsum = 0.f;     // running denom for q = q0 + l15
    const int qrow = q0 + l15;

#define STAGE(buf, ktile) do {                                                     \
        const __bf16* kbase = Kp + (size_t)(ktile) * 64 * HDIM;                    \
        _Pragma("unroll")                                                          \
        for (int i_ = 0; i_ < 4; ++i_) {                                           \
            int c_ = i_ * 256 + tid;            /* 1024 chunks = 64x128 bf16 */    \
            int row_ = c_ >> 4, cc_ = (c_ & 15) ^ (row_ & 7);                      \
            GLDS16(kbase + (size_t)row_ * HDIM + cc_ * 8,                          \
                   (char*)Ks[buf] + c_ * 16);                                      \
        }                                                                          \
        const __bf16* vbase = Vp + (size_t)(ktile) * 64;                           \
        _Pragma("unroll")                                                          \
        for (int i_ = 0; i_ < 4; ++i_) {                                           \
            int c_ = i_ * 256 + tid;            /* 1024 chunks = 128x64 bf16 */    \
            int row_ = c_ >> 3, cc_ = (c_ & 7) ^ (row_ & 7);                       \
            GLDS16(vbase + (size_t)row_ * S_LEN + cc_ * 8,                         \
                   (char*)Vs[buf] + c_ * 16);                                      \
        }                                                                          \
    } while (0)

    const int nkt = qt + 1;
    int cur = 0;
    STAGE(0, 0);
    __syncthreads();   // drains vmcnt(0): tile 0 ready

    for (int kt = 0; kt < nkt; ++kt) {
        if (kt + 1 < nkt) STAGE(cur ^ 1, kt + 1);   // prefetch next tile
        // ---- scores (swapped): S[k = fn*16 + l4*4 + r][q = q0 + l15] ----
        f32x4 sfr[4];
        __builtin_amdgcn_s_setprio(1);
#pragma unroll
        for (int fn = 0; fn < 4; ++fn) {
            f32x4 sa = {};
#pragma unroll
            for (int kk = 0; kk < 4; ++kk) {
                int row = fn * 16 + l15;
                int cc = (kk * 4 + l4) ^ (l15 & 7);
                bf16x8 kb = *(const bf16x8*)(Ks[cur] + row * HDIM + cc * 8);
                sa = __builtin_amdgcn_mfma_f32_16x16x32_bf16(kb, qf[kk], sa, 0, 0, 0);
            }
            sfr[fn] = sa;
        }
        __builtin_amdgcn_s_setprio(0);
        // ---- softmax (mostly lane-local; reduce only over l4 dim) ----
        const bool last = (kt == nkt - 1);
        float sv[16];
        float pmax = -1e30f;
#pragma unroll
        for (int fn = 0; fn < 4; ++fn)
#pragma unroll
            for (int r = 0; r < 4; ++r) {
                float v = sfr[fn][r];
                if (last) {
                    int kcol = kt * 64 + fn * 16 + l4 * 4 + r;
                    if (kcol > qrow) v = -1e30f;
                }
                sv[fn * 4 + r] = v;
                pmax = fmaxf(pmax, v);
            }
        pmax = fmaxf(pmax, __shfl_xor(pmax, 16));
        pmax = fmaxf(pmax, __shfl_xor(pmax, 32));
        if (!__all(pmax - m <= 8.0f)) {          // defer-max: rescale rarely
            float mn = fmaxf(m, pmax);
            float alpha = exp2f((m - mn) * L2E);
            m = mn;
            lsum *= alpha;
#pragma unroll
            for (int r = 0; r < 4; ++r) {
                float ar = __shfl(alpha, l4 * 4 + r, 16);
#pragma unroll
                for (int n = 0; n < 8; ++n) acc[n][r] *= ar;
            }
        }
        float rs = 0.f;
#pragma unroll
        for (int fn = 0; fn < 4; ++fn) {
            bf16x4 pk;
#pragma unroll
            for (int r = 0; r < 4; ++r) {
                float p = exp2f((sv[fn * 4 + r] - m) * L2E);
                rs += p;
                pk[r] = (__bf16)p;
            }
            *(bf16x4*)(&Pl[w][l15][fn * 16 + l4 * 4]) = pk;   // ds_write_b64
        }
        rs += __shfl_xor(rs, 16);
        rs += __shfl_xor(rs, 32);
        lsum += rs;
        asm volatile("s_waitcnt lgkmcnt(0)" ::: "memory");
        __builtin_amdgcn_sched_barrier(0);
        // ---- PV ----
        __builtin_amdgcn_s_setprio(1);
#pragma unroll
        for (int kk = 0; kk < 2; ++kk) {
            bf16x8 pa = *(const bf16x8*)(&Pl[w][l15][kk * 32 + l4 * 8]);
#pragma unroll
            for (int n = 0; n < 8; ++n) {
                int row = n * 16 + l15;
                int cc = (kk * 4 + l4) ^ (l15 & 7);
                bf16x8 vb = *(const bf16x8*)(Vs[cur] + row * 64 + cc * 8);
                acc[n] = __builtin_amdgcn_mfma_f32_16x16x32_bf16(pa, vb, acc[n], 0, 0, 0);
            }
        }
        __builtin_amdgcn_s_setprio(0);
        __syncthreads();   // drains vmcnt(0) (next tile ready) + lgkmcnt
        cur ^= 1;
    }
#undef STAGE
    // ---- epilogue: attn[b, row, h*128 + d] ----
#pragma unroll
    for (int r = 0; r < 4; ++r) {
        float inv = 1.0f / __shfl(lsum, l4 * 4 + r, 16);
        int row = q0 + l4 * 4 + r;
#pragma unroll
        for (int n = 0; n < 8; ++n)
            O[((size_t)(b * S_LEN) + row) * QSZ + h * HDIM + n * 16 + l15] = (__bf16)(acc[n][r] * inv);
    }
}

extern "C" void kernel_launch(void* const* d_in, const int* in_sizes, int n_in,
                              void* d_out, int out_size, void* d_ws, size_t ws_size,
                              hipStream_t stream) {
    const int*   pos    = (const int*)d_in[0];
    const float* hidden = (const float*)d_in[1];
    const float* wqkv   = (const float*)d_in[2];
    const float* wo     = (const float*)d_in[3];
    float* out = (float*)d_out;

    // workspace carve
    __bf16* hb    = (__bf16*)d_ws;                     // 16,777,216 elems
    __bf16* wqb   = hb  + 16777216;                    // 25,165,824
    __bf16* wob   = wqb + 25165824;                    // 16,777,216
    float*  qkv   = (float*)(wob + 16777216);          // 25,165,824 f32
    __bf16* Qb    = (__bf16*)(qkv + 25165824);         // 16,777,216
    __bf16* Kb    = Qb  + 16777216;                    // 4,194,304
    __bf16* Vtb   = Kb  + 4194304;                     // 4,194,304
    __bf16* attnb = Vtb + 4194304;                     // 16,777,216
    float*  rc    = (float*)(attnb + 16777216);        // 131,072
    float*  rs    = rc + 131072;                       // 131,072

    conv_f32_bf16<<<16384, 256, 0, stream>>>(hidden, hb, 4194304);
    conv_f32_bf16<<<24576, 256, 0, stream>>>(wqkv, wqb, 6291456);
    conv_f32_bf16<<<16384, 256, 0, stream>>>(wo, wob, 4194304);
    rope_table_kernel<<<512, 256, 0, stream>>>(rc, rs);
    gemm256<<<dim3(QKVSZ / 256, (B_DIM * S_LEN) / 256), 512, 0, stream>>>(hb, wqb, qkv, QKVSZ);
    rope_kernel<<<B_DIM * S_LEN, 256, 0, stream>>>(qkv, pos, rc, rs, Qb, Kb);
    vtrans_kernel<<<dim3(S_LEN / 64, NKV, B_DIM), 256, 0, stream>>>(qkv, Vtb);
    attn_kernel<<<dim3(S_LEN / 64, NHEADS, B_DIM), 256, 0, stream>>>(Qb, Kb, Vtb, attnb);
    gemm256<<<dim3(HIDDEN / 256, (B_DIM * S_LEN) / 256), 512, 0, stream>>>(attnb, wob, out, HIDDEN);
}

// Round 6
// 660.700 us; speedup vs baseline: 2.2346x; 1.0809x over previous
//
#include <hip/hip_runtime.h>
#include <hip/hip_bf16.h>
#include <cmath>

typedef __bf16 bf16x8 __attribute__((ext_vector_type(8)));
typedef __bf16 bf16x4 __attribute__((ext_vector_type(4)));
typedef float  f32x4  __attribute__((ext_vector_type(4)));

#define AS1 __attribute__((address_space(1)))
#define AS3 __attribute__((address_space(3)))
#define GLDS16(gp, lp) __builtin_amdgcn_global_load_lds((AS1 void*)(gp), (AS3 void*)(lp), 16, 0, 0)

#define B_DIM 2
#define S_LEN 2048
#define HIDDEN 4096
#define NHEADS 32
#define NKV 8
#define HDIM 128
#define QSZ 4096
#define KVSZ 1024
#define QKVSZ 6144
#define GK 4096                /* K of both GEMMs */
#define ATT_SCALE 0.0078125f   /* 1/128, folded into Qb at RoPE time */
#define L2E 1.4426950408889634f

// ---------------- f32 -> bf16 conversion (vectorized) ----------------
__global__ __launch_bounds__(256) void conv_f32_bf16(const float* __restrict__ in,
                                                     __bf16* __restrict__ out, int n4) {
    int idx = blockIdx.x * 256 + threadIdx.x;
    if (idx < n4) {
        float4 v = ((const float4*)in)[idx];
        bf16x4 o;
        o[0] = (__bf16)v.x; o[1] = (__bf16)v.y; o[2] = (__bf16)v.z; o[3] = (__bf16)v.w;
        ((bf16x4*)out)[idx] = o;
    }
}

// ---------------- RoPE cos/sin table: [pos][i], i<64 ----------------
__global__ __launch_bounds__(256) void rope_table_kernel(float* __restrict__ ct,
                                                         float* __restrict__ st) {
    int idx = blockIdx.x * 256 + threadIdx.x;   // S_LEN*64 entries
    int p = idx >> 6, i = idx & 63;
    float inv = expf(-(float)i * (9.210340371976184f / 64.0f));
    float freq = (float)p * inv;
    float s, c;
    sincosf(freq, &s, &c);
    ct[idx] = c; st[idx] = s;
}

// ---------------- 256x256 8-phase GEMM: C[m,n] = sum_k A[m,k]*B[n,k] ----------------
// A [M,GK], B [N,GK] bf16 row-major; C [M,N] OUT-typed. M,N mult of 256; GK=4096.
template<typename OUT>
__global__ __launch_bounds__(512, 2) void gemm256(const __bf16* __restrict__ A,
                                                  const __bf16* __restrict__ B,
                                                  OUT* __restrict__ C,
                                                  int N) {
    __shared__ __bf16 Asm[2 * 16384 + 2 * 16384];   // A: 2 slots x 32KB, B: 2 slots x 32KB
    char* Bbase = (char*)Asm + 65536;

    const int tid = threadIdx.x;
    const int w = tid >> 6, l = tid & 63;
    const int l15 = l & 15, l4 = l >> 4;
    const int wr = w >> 2, wc = w & 3;

    // XCD-bijective swizzle (nwg % 8 == 0 for both call sites)
    const int nwg = gridDim.x * gridDim.y;
    const int orig = blockIdx.y * gridDim.x + blockIdx.x;
    const int swz = (orig & 7) * (nwg >> 3) + (orig >> 3);
    const int bx = swz % gridDim.x, by = swz / gridDim.x;
    const int m0 = by * 256, n0 = bx * 256;

    const __bf16* Ag = A + (size_t)m0 * GK;
    const __bf16* Bg = B + (size_t)n0 * GK;

#define STAGE_AQ(q, tile) do {                                                  \
        int c_ = (q) * 512 + tid;                                               \
        int r_ = c_ >> 3;                                                       \
        int jg_ = (tid & 7) ^ (r_ & 7);                                         \
        GLDS16(Ag + (size_t)r_ * GK + (tile) * 64 + jg_ * 8,                    \
               (char*)Asm + ((tile) & 1) * 32768 + c_ * 16);                    \
    } while (0)
#define STAGE_BS(s, tile) do {                                                  \
        _Pragma("unroll")                                                       \
        for (int i_ = 0; i_ < 2; ++i_) {                                        \
            int v_ = i_ * 512 + tid;                                            \
            int r_ = (v_ >> 8) * 64 + (s) * 32 + ((v_ >> 3) & 31);              \
            int jg_ = (v_ & 7) ^ (r_ & 7);                                      \
            int c_ = r_ * 8 + (v_ & 7);                                         \
            GLDS16(Bg + (size_t)r_ * GK + (tile) * 64 + jg_ * 8,                \
                   Bbase + ((tile) & 1) * 32768 + c_ * 16);                     \
        }                                                                       \
    } while (0)

    f32x4 acc[8][4] = {};

    const int T = GK / 64;   // 64 K-tiles
    STAGE_AQ(0, 0); STAGE_AQ(1, 0); STAGE_AQ(2, 0); STAGE_AQ(3, 0);
    STAGE_BS(0, 0); STAGE_BS(1, 0);
    STAGE_AQ(0, 1); STAGE_AQ(2, 1); STAGE_BS(0, 1);
    asm volatile("s_waitcnt vmcnt(4)" ::: "memory");
    __builtin_amdgcn_s_barrier();

#define PHASE(MH, NH, STAGES, WAITS)                                            \
    {                                                                           \
        bf16x8 af[4][2], bfr[2][2];                                             \
        _Pragma("unroll")                                                       \
        for (int m2 = 0; m2 < 4; ++m2) {                                        \
            int row = wr * 128 + ((MH) * 4 + m2) * 16 + l15;                    \
            _Pragma("unroll")                                                   \
            for (int kk = 0; kk < 2; ++kk) {                                    \
                int j = (kk * 4 + l4) ^ (row & 7);                              \
                af[m2][kk] = *(const bf16x8*)(Als + row * 64 + j * 8);          \
            }                                                                   \
        }                                                                       \
        _Pragma("unroll")                                                       \
        for (int n2 = 0; n2 < 2; ++n2) {                                        \
            int row = wc * 64 + ((NH) * 2 + n2) * 16 + l15;                     \
            _Pragma("unroll")                                                   \
            for (int kk = 0; kk < 2; ++kk) {                                    \
                int j = (kk * 4 + l4) ^ (row & 7);                              \
                bfr[n2][kk] = *(const bf16x8*)(Bls + row * 64 + j * 8);         \
            }                                                                   \
        }                                                                       \
        STAGES;                                                                 \
        __builtin_amdgcn_sched_barrier(0);                                      \
        __builtin_amdgcn_s_barrier();                                           \
        asm volatile("s_waitcnt lgkmcnt(0)" ::: "memory");                      \
        __builtin_amdgcn_sched_barrier(0);                                      \
        __builtin_amdgcn_s_setprio(1);                                          \
        _Pragma("unroll")                                                       \
        for (int m2 = 0; m2 < 4; ++m2)                                          \
            _Pragma("unroll")                                                   \
            for (int n2 = 0; n2 < 2; ++n2)                                      \
                _Pragma("unroll")                                               \
                for (int kk = 0; kk < 2; ++kk)                                  \
                    acc[(MH) * 4 + m2][(NH) * 2 + n2] =                         \
                        __builtin_amdgcn_mfma_f32_16x16x32_bf16(                \
                            af[m2][kk], bfr[n2][kk],                            \
                            acc[(MH) * 4 + m2][(NH) * 2 + n2], 0, 0, 0);        \
        __builtin_amdgcn_s_setprio(0);                                          \
        WAITS;                                                                  \
        __builtin_amdgcn_sched_barrier(0);                                      \
        __builtin_amdgcn_s_barrier();                                           \
    }

    for (int t = 0; t < T; ++t) {
        const int slot = t & 1;
        const __bf16* Als = Asm + slot * 16384;
        const __bf16* Bls = (__bf16*)Bbase + slot * 16384;
        PHASE(0, 0,
              { if (t + 1 < T) { STAGE_AQ(1, t + 1); STAGE_AQ(3, t + 1); } },
              {});
        PHASE(0, 1,
              { if (t + 1 < T) { STAGE_BS(1, t + 1); } },
              {});
        PHASE(1, 0,
              { if (t + 2 < T) { STAGE_AQ(0, t + 2); STAGE_AQ(2, t + 2); } },
              {});
        PHASE(1, 1,
              { if (t + 2 < T) { STAGE_BS(0, t + 2); } },
              {
                  if (t + 2 < T)      { asm volatile("s_waitcnt vmcnt(4)" ::: "memory"); }
                  else if (t + 1 < T) { asm volatile("s_waitcnt vmcnt(0)" ::: "memory"); }
              });
    }
#undef PHASE
#undef STAGE_AQ
#undef STAGE_BS

#pragma unroll
    for (int mi = 0; mi < 8; ++mi)
#pragma unroll
        for (int ni = 0; ni < 4; ++ni)
#pragma unroll
            for (int r = 0; r < 4; ++r)
                C[(size_t)(m0 + wr * 128 + mi * 16 + l4 * 4 + r) * N
                  + n0 + wc * 64 + ni * 16 + l15] = (OUT)acc[mi][ni][r];
}

// ---------------- RoPE apply: qkv bf16 -> Q (pre-scaled) [B,32,S,128], K [B,8,S,128] bf16 ----------------
__global__ __launch_bounds__(256) void rope_kernel(const __bf16* __restrict__ qkv,
                                                   const int* __restrict__ pos,
                                                   const float* __restrict__ ct,
                                                   const float* __restrict__ st,
                                                   __bf16* __restrict__ Qb,
                                                   __bf16* __restrict__ Kb) {
    const int tid = threadIdx.x;
    const int tok = blockIdx.x;                 // 0..B*S-1
    const int b = tok >> 11, s = tok & 2047;
    const int p = pos[tok];
    const __bf16* base = qkv + (size_t)tok * QKVSZ;
    const float* cb = ct + (size_t)p * 64;
    const float* sb = st + (size_t)p * 64;
    for (int idx = tid; idx < 2560; idx += 256) {   // (32+8)*64 pairs
        int head = idx >> 6, i = idx & 63;
        float c = cb[i], sn = sb[i];
        if (head < 32) {
            float x1 = (float)base[head * HDIM + i];
            float x2 = (float)base[head * HDIM + 64 + i];
            size_t o = ((size_t)(b * 32 + head) * S_LEN + s) * HDIM + i;
            Qb[o]      = (__bf16)((x1 * c - x2 * sn) * ATT_SCALE);
            Qb[o + 64] = (__bf16)((x2 * c + x1 * sn) * ATT_SCALE);
        } else {
            int g = head - 32;
            float x1 = (float)base[QSZ + g * HDIM + i];
            float x2 = (float)base[QSZ + g * HDIM + 64 + i];
            size_t o = ((size_t)(b * 8 + g) * S_LEN + s) * HDIM + i;
            Kb[o]      = (__bf16)(x1 * c - x2 * sn);
            Kb[o + 64] = (__bf16)(x2 * c + x1 * sn);
        }
    }
}

// ---------------- V transpose: qkv bf16 V-slice -> Vt [B,8,128,S] bf16 ----------------
__global__ __launch_bounds__(256) void vtrans_kernel(const __bf16* __restrict__ qkv,
                                                     __bf16* __restrict__ Vt) {
    __shared__ __bf16 T[64][132];
    const int tid = threadIdx.x;
    const int st = blockIdx.x, g = blockIdx.y, b = blockIdx.z;
    const __bf16* src = qkv + ((size_t)(b * S_LEN + st * 64)) * QKVSZ + (QSZ + KVSZ) + g * HDIM;
#pragma unroll
    for (int it = 0; it < 8; ++it) {
        int c = it * 256 + tid;       // 0..2047, 32 4-elem chunks per row
        int row = c >> 5;
        int c4 = c & 31;
        bf16x4 v = *(const bf16x4*)(src + (size_t)row * QKVSZ + c4 * 4);
        *(bf16x4*)(&T[row][c4 * 4]) = v;
    }
    __syncthreads();
#pragma unroll
    for (int it = 0; it < 8; ++it) {
        int c = it * 256 + tid;       // 0..2047, 16 chunks (of 4 s-cols) per d-row
        int d = c >> 4;
        int s4 = (c & 15) * 4;
        bf16x4 o;
        o[0] = T[s4 + 0][d]; o[1] = T[s4 + 1][d]; o[2] = T[s4 + 2][d]; o[3] = T[s4 + 3][d];
        *(bf16x4*)(Vt + ((size_t)(b * 8 + g) * HDIM + d) * S_LEN + st * 64 + s4) = o;
    }
}

// ---------------- Flash attention (causal, GQA rep=4) ----------------
// QBLK=128 (4 waves x 32 q-rows), KVBLK=64. Swapped QK^T (mfma(K,Q)),
// lane-local softmax, defer-max. K/V double-buffered swizzled LDS (64KB) +
// P buffer [4][32][64] XOR-swizzled (16KB) = 81920 B -> 2 blocks/CU.
__global__ __launch_bounds__(256, 2) void attn_kernel(const __bf16* __restrict__ Q,
                                                      const __bf16* __restrict__ K,
                                                      const __bf16* __restrict__ Vt,
                                                      __bf16* __restrict__ O) {
    const int tid = threadIdx.x;
    const int w = tid >> 6, l = tid & 63;
    const int l15 = l & 15, l4 = l >> 4;
    const int qt = gridDim.x - 1 - blockIdx.x;   // reversed: long blocks first
    const int h = blockIdx.y, b = blockIdx.z;
    const int g = h >> 2;
    const int qw0 = qt * 128 + w * 32;           // wave's first q-row

    __shared__ __bf16 Ks[2][64 * 128];   // 2x16 KB; chunk c: row=c>>4, cc=(c&15)^(row&7)
    __shared__ __bf16 Vs[2][128 * 64];   // 2x16 KB; chunk c: row=c>>3, cc=(c&7)^(row&7)
    __shared__ __bf16 Pl[4 * 32 * 64];   // 16 KB; per-wave P[q][chunk^((q&3)<<2)]

    const __bf16* Qp = Q + ((size_t)((b * 32 + h) * S_LEN + qw0)) * HDIM;
    const __bf16* Kp = K + (size_t)(b * 8 + g) * S_LEN * HDIM;
    const __bf16* Vp = Vt + (size_t)(b * 8 + g) * HDIM * S_LEN;

    bf16x8 qf[2][4];
#pragma unroll
    for (int qh = 0; qh < 2; ++qh)
#pragma unroll
        for (int kk = 0; kk < 4; ++kk)
            qf[qh][kk] = *(const bf16x8*)(Qp + (size_t)(qh * 16 + l15) * HDIM + kk * 32 + l4 * 8);

    f32x4 acc[2][8] = {};
    float m[2]    = {-1e30f, -1e30f};
    float lsum[2] = {0.f, 0.f};

#define STAGE(buf, ktile) do {                                                     \
        const __bf16* kbase = Kp + (size_t)(ktile) * 64 * HDIM;                    \
        _Pragma("unroll")                                                          \
        for (int i_ = 0; i_ < 4; ++i_) {                                           \
            int c_ = i_ * 256 + tid;            /* 1024 chunks = 64x128 bf16 */    \
            int row_ = c_ >> 4, cc_ = (c_ & 15) ^ (row_ & 7);                      \
            GLDS16(kbase + (size_t)row_ * HDIM + cc_ * 8,                          \
                   (char*)Ks[buf] + c_ * 16);                                      \
        }                                                                          \
        const __bf16* vbase = Vp + (size_t)(ktile) * 64;                           \
        _Pragma("unroll")                                                          \
        for (int i_ = 0; i_ < 4; ++i_) {                                           \
            int c_ = i_ * 256 + tid;            /* 1024 chunks = 128x64 bf16 */    \
            int row_ = c_ >> 3, cc_ = (c_ & 7) ^ (row_ & 7);                       \
            GLDS16(vbase + (size_t)row_ * S_LEN + cc_ * 8,                         \
                   (char*)Vs[buf] + c_ * 16);                                      \
        }                                                                          \
    } while (0)

    const int nkt = 2 * qt + 2;
    int cur = 0;
    STAGE(0, 0);
    __syncthreads();   // drains vmcnt(0): tile 0 ready

    for (int kt = 0; kt < nkt; ++kt) {
        if (kt + 1 < nkt) STAGE(cur ^ 1, kt + 1);   // prefetch next tile
        if (kt * 64 <= qw0 + 31) {                  // wave-level causal skip
            // ---- scores (swapped): S[k = fn*16 + l4*4 + r][q = qw0 + qh*16 + l15] ----
            f32x4 sfr[2][4];
            __builtin_amdgcn_s_setprio(1);
#pragma unroll
            for (int fn = 0; fn < 4; ++fn) {
                f32x4 sa0 = {}, sa1 = {};
#pragma unroll
                for (int kk = 0; kk < 4; ++kk) {
                    int row = fn * 16 + l15;
                    int cc = (kk * 4 + l4) ^ (l15 & 7);
                    bf16x8 kb = *(const bf16x8*)(Ks[cur] + row * HDIM + cc * 8);
                    sa0 = __builtin_amdgcn_mfma_f32_16x16x32_bf16(kb, qf[0][kk], sa0, 0, 0, 0);
                    sa1 = __builtin_amdgcn_mfma_f32_16x16x32_bf16(kb, qf[1][kk], sa1, 0, 0, 0);
                }
                sfr[0][fn] = sa0; sfr[1][fn] = sa1;
            }
            __builtin_amdgcn_s_setprio(0);
            const bool needmask = (kt * 64 + 63 > qw0);
#pragma unroll
            for (int qh = 0; qh < 2; ++qh) {
                const int qrow = qw0 + qh * 16 + l15;
                float pmax = -1e30f;
#pragma unroll
                for (int fn = 0; fn < 4; ++fn)
#pragma unroll
                    for (int r = 0; r < 4; ++r) {
                        float v = sfr[qh][fn][r];
                        if (needmask) {
                            int kcol = kt * 64 + fn * 16 + l4 * 4 + r;
                            if (kcol > qrow) v = -1e30f;
                        }
                        sfr[qh][fn][r] = v;
                        pmax = fmaxf(pmax, v);
                    }
                pmax = fmaxf(pmax, __shfl_xor(pmax, 16));
                pmax = fmaxf(pmax, __shfl_xor(pmax, 32));
                if (!__all(pmax - m[qh] <= 8.0f)) {          // defer-max
                    float mn = fmaxf(m[qh], pmax);
                    float alpha = exp2f((m[qh] - mn) * L2E);
                    m[qh] = mn;
                    lsum[qh] *= alpha;
#pragma unroll
                    for (int r = 0; r < 4; ++r) {
                        float ar = __shfl(alpha, l4 * 4 + r, 16);
#pragma unroll
                        for (int n = 0; n < 8; ++n) acc[qh][n][r] *= ar;
                    }
                }
                float rs = 0.f;
#pragma unroll
                for (int fn = 0; fn < 4; ++fn) {
                    bf16x4 pk;
#pragma unroll
                    for (int r = 0; r < 4; ++r) {
                        float p = exp2f((sfr[qh][fn][r] - m[qh]) * L2E);
                        rs += p;
                        pk[r] = (__bf16)p;
                    }
                    *(bf16x4*)(Pl + w * 2048 + (qh * 16 + l15) * 64
                               + (((fn * 4 + l4) ^ ((l15 & 3) << 2)) * 4)) = pk;
                }
                rs += __shfl_xor(rs, 16);
                rs += __shfl_xor(rs, 32);
                lsum[qh] += rs;
            }
            asm volatile("s_waitcnt lgkmcnt(0)" ::: "memory");
            __builtin_amdgcn_sched_barrier(0);
            // ---- PV ----
            __builtin_amdgcn_s_setprio(1);
#pragma unroll
            for (int kk = 0; kk < 2; ++kk) {
                int pc = ((kk * 8 + l4 * 2) ^ ((l15 & 3) << 2)) * 4;
                bf16x8 pa0 = *(const bf16x8*)(Pl + w * 2048 + l15 * 64 + pc);
                bf16x8 pa1 = *(const bf16x8*)(Pl + w * 2048 + (16 + l15) * 64 + pc);
#pragma unroll
                for (int n = 0; n < 8; ++n) {
                    int row = n * 16 + l15;
                    int cc = (kk * 4 + l4) ^ (l15 & 7);
                    bf16x8 vb = *(const bf16x8*)(Vs[cur] + row * 64 + cc * 8);
                    acc[0][n] = __builtin_amdgcn_mfma_f32_16x16x32_bf16(pa0, vb, acc[0][n], 0, 0, 0);
                    acc[1][n] = __builtin_amdgcn_mfma_f32_16x16x32_bf16(pa1, vb, acc[1][n], 0, 0, 0);
                }
            }
            __builtin_amdgcn_s_setprio(0);
        }
        __syncthreads();   // drains vmcnt(0) (next tile ready) + lgkmcnt
        cur ^= 1;
    }
#undef STAGE
    // ---- epilogue: attn[b, row, h*128 + d] ----
#pragma unroll
    for (int qh = 0; qh < 2; ++qh)
#pragma unroll
        for (int r = 0; r < 4; ++r) {
            float inv = 1.0f / __shfl(lsum[qh], l4 * 4 + r, 16);
            int row = qw0 + qh * 16 + l4 * 4 + r;
#pragma unroll
            for (int n = 0; n < 8; ++n)
                O[((size_t)(b * S_LEN) + row) * QSZ + h * HDIM + n * 16 + l15] = (__bf16)(acc[qh][n][r] * inv);
        }
}

extern "C" void kernel_launch(void* const* d_in, const int* in_sizes, int n_in,
                              void* d_out, int out_size, void* d_ws, size_t ws_size,
                              hipStream_t stream) {
    const int*   pos    = (const int*)d_in[0];
    const float* hidden = (const float*)d_in[1];
    const float* wqkv   = (const float*)d_in[2];
    const float* wo     = (const float*)d_in[3];
    float* out = (float*)d_out;

    // workspace carve
    __bf16* hb    = (__bf16*)d_ws;                     // 16,777,216 elems
    __bf16* wqb   = hb  + 16777216;                    // 25,165,824
    __bf16* wob   = wqb + 25165824;                    // 16,777,216
    __bf16* qkv   = wob + 16777216;                    // 25,165,824 bf16
    __bf16* Qb    = qkv + 25165824;                    // 16,777,216
    __bf16* Kb    = Qb  + 16777216;                    // 4,194,304
    __bf16* Vtb   = Kb  + 4194304;                     // 4,194,304
    __bf16* attnb = Vtb + 4194304;                     // 16,777,216
    float*  rc    = (float*)(attnb + 16777216);        // 131,072
    float*  rs    = rc + 131072;                       // 131,072

    conv_f32_bf16<<<16384, 256, 0, stream>>>(hidden, hb, 4194304);
    conv_f32_bf16<<<24576, 256, 0, stream>>>(wqkv, wqb, 6291456);
    conv_f32_bf16<<<16384, 256, 0, stream>>>(wo, wob, 4194304);
    rope_table_kernel<<<512, 256, 0, stream>>>(rc, rs);
    gemm256<__bf16><<<dim3(QKVSZ / 256, (B_DIM * S_LEN) / 256), 512, 0, stream>>>(hb, wqb, qkv, QKVSZ);
    rope_kernel<<<B_DIM * S_LEN, 256, 0, stream>>>(qkv, pos, rc, rs, Qb, Kb);
    vtrans_kernel<<<dim3(S_LEN / 64, NKV, B_DIM), 256, 0, stream>>>(qkv, Vtb);
    attn_kernel<<<dim3(S_LEN / 128, NHEADS, B_DIM), 256, 0, stream>>>(Qb, Kb, Vtb, attnb);
    gemm256<float><<<dim3(HIDDEN / 256, (B_DIM * S_LEN) / 256), 512, 0, stream>>>(attnb, wob, out, HIDDEN);
}

// Round 7
// 617.711 us; speedup vs baseline: 2.3901x; 1.0696x over previous
//
#include <hip/hip_runtime.h>
#include <hip/hip_bf16.h>
#include <cmath>

typedef __bf16 bf16x8 __attribute__((ext_vector_type(8)));
typedef __bf16 bf16x4 __attribute__((ext_vector_type(4)));
typedef float  f32x4  __attribute__((ext_vector_type(4)));

#define AS1 __attribute__((address_space(1)))
#define AS3 __attribute__((address_space(3)))
#define GLDS16(gp, lp) __builtin_amdgcn_global_load_lds((AS1 void*)(gp), (AS3 void*)(lp), 16, 0, 0)

#define B_DIM 2
#define S_LEN 2048
#define HIDDEN 4096
#define NHEADS 32
#define NKV 8
#define HDIM 128
#define QSZ 4096
#define KVSZ 1024
#define QKVSZ 6144
#define GK 4096                /* K of both GEMMs */
#define ATT_SCALE 0.0078125f   /* 1/128, folded into Qb at RoPE time */
#define L2E 1.4426950408889634f

// ---------------- f32 -> bf16 conversion (vectorized) ----------------
__global__ __launch_bounds__(256) void conv_f32_bf16(const float* __restrict__ in,
                                                     __bf16* __restrict__ out, int n4) {
    int idx = blockIdx.x * 256 + threadIdx.x;
    if (idx < n4) {
        float4 v = ((const float4*)in)[idx];
        bf16x4 o;
        o[0] = (__bf16)v.x; o[1] = (__bf16)v.y; o[2] = (__bf16)v.z; o[3] = (__bf16)v.w;
        ((bf16x4*)out)[idx] = o;
    }
}

// ---------------- RoPE cos/sin table: [pos][i], i<64 ----------------
__global__ __launch_bounds__(256) void rope_table_kernel(float* __restrict__ ct,
                                                         float* __restrict__ st) {
    int idx = blockIdx.x * 256 + threadIdx.x;   // S_LEN*64 entries
    int p = idx >> 6, i = idx & 63;
    float inv = expf(-(float)i * (9.210340371976184f / 64.0f));
    float freq = (float)p * inv;
    float s, c;
    sincosf(freq, &s, &c);
    ct[idx] = c; st[idx] = s;
}

// ---------------- 256x256 4-phase/K-tile GEMM, A-fragment residency ----------------
// A [M,GK], B [N,GK] bf16 row-major; C [M,N] OUT-typed. M,N mult of 256; GK=4096.
template<typename OUT>
__global__ __launch_bounds__(512, 2) void gemm256(const __bf16* __restrict__ A,
                                                  const __bf16* __restrict__ B,
                                                  OUT* __restrict__ C,
                                                  int N) {
    __shared__ __bf16 Asm[2 * 16384 + 2 * 16384];   // A: 2 slots x 32KB, B: 2 slots x 32KB
    char* Bbase = (char*)Asm + 65536;

    const int tid = threadIdx.x;
    const int w = tid >> 6, l = tid & 63;
    const int l15 = l & 15, l4 = l >> 4;
    const int wr = w >> 2, wc = w & 3;

    // XCD-bijective swizzle (nwg % 8 == 0 for both call sites)
    const int nwg = gridDim.x * gridDim.y;
    const int orig = blockIdx.y * gridDim.x + blockIdx.x;
    const int swz = (orig & 7) * (nwg >> 3) + (orig >> 3);
    const int bx = swz % gridDim.x, by = swz / gridDim.x;
    const int m0 = by * 256, n0 = bx * 256;

    const __bf16* Ag = A + (size_t)m0 * GK;
    const __bf16* Bg = B + (size_t)n0 * GK;

#define STAGE_AQ(q, tile) do {                                                  \
        int c_ = (q) * 512 + tid;                                               \
        int r_ = c_ >> 3;                                                       \
        int jg_ = (tid & 7) ^ (r_ & 7);                                         \
        GLDS16(Ag + (size_t)r_ * GK + (tile) * 64 + jg_ * 8,                    \
               (char*)Asm + ((tile) & 1) * 32768 + c_ * 16);                    \
    } while (0)
#define STAGE_BS(s, tile) do {                                                  \
        _Pragma("unroll")                                                       \
        for (int i_ = 0; i_ < 2; ++i_) {                                        \
            int v_ = i_ * 512 + tid;                                            \
            int r_ = (v_ >> 8) * 64 + (s) * 32 + ((v_ >> 3) & 31);              \
            int jg_ = (v_ & 7) ^ (r_ & 7);                                      \
            int c_ = r_ * 8 + (v_ & 7);                                         \
            GLDS16(Bg + (size_t)r_ * GK + (tile) * 64 + jg_ * 8,                \
                   Bbase + ((tile) & 1) * 32768 + c_ * 16);                     \
        }                                                                       \
    } while (0)

#define LOAD_A(DST, MH) do {                                                    \
        _Pragma("unroll")                                                       \
        for (int m2 = 0; m2 < 4; ++m2) {                                        \
            int row = wr * 128 + ((MH) * 4 + m2) * 16 + l15;                    \
            _Pragma("unroll")                                                   \
            for (int kk = 0; kk < 2; ++kk) {                                    \
                int j = (kk * 4 + l4) ^ (row & 7);                              \
                DST[m2][kk] = *(const bf16x8*)(Als + row * 64 + j * 8);         \
            }                                                                   \
        }                                                                       \
    } while (0)
#define LOAD_B(DST, NH) do {                                                    \
        _Pragma("unroll")                                                       \
        for (int n2 = 0; n2 < 2; ++n2) {                                        \
            int row = wc * 64 + ((NH) * 2 + n2) * 16 + l15;                     \
            _Pragma("unroll")                                                   \
            for (int kk = 0; kk < 2; ++kk) {                                    \
                int j = (kk * 4 + l4) ^ (row & 7);                              \
                DST[n2][kk] = *(const bf16x8*)(Bls + row * 64 + j * 8);         \
            }                                                                   \
        }                                                                       \
    } while (0)
#define MFMA_QUAD(AF, BF, MI0, NI0)                                             \
    _Pragma("unroll")                                                           \
    for (int m2 = 0; m2 < 4; ++m2)                                              \
        _Pragma("unroll")                                                       \
        for (int n2 = 0; n2 < 2; ++n2)                                          \
            _Pragma("unroll")                                                   \
            for (int kk = 0; kk < 2; ++kk)                                      \
                acc[(MI0) + m2][(NI0) + n2] =                                   \
                    __builtin_amdgcn_mfma_f32_16x16x32_bf16(                    \
                        AF[m2][kk], BF[n2][kk], acc[(MI0) + m2][(NI0) + n2], 0, 0, 0);
#define PH_SYNC_PRE  do { __builtin_amdgcn_sched_barrier(0);                    \
        __builtin_amdgcn_s_barrier();                                           \
        asm volatile("s_waitcnt lgkmcnt(0)" ::: "memory");                      \
        __builtin_amdgcn_sched_barrier(0); } while (0)
#define PH_SYNC_POST do { __builtin_amdgcn_sched_barrier(0);                    \
        __builtin_amdgcn_s_barrier(); } while (0)

    f32x4 acc[8][4] = {};

    const int T = GK / 64;   // 64 K-tiles
    // ---- prologue: tile 0 fully + A1,A3 handled in-loop; here: tile0 + A0,A2,BS0 of tile1 pattern ----
    STAGE_AQ(0, 0); STAGE_AQ(1, 0); STAGE_AQ(2, 0); STAGE_AQ(3, 0);
    STAGE_BS(0, 0); STAGE_BS(1, 0);
    STAGE_AQ(0, 1); STAGE_AQ(2, 1); STAGE_BS(0, 1);
    asm volatile("s_waitcnt vmcnt(4)" ::: "memory");
    __builtin_amdgcn_s_barrier();

    for (int t = 0; t < T; ++t) {
        const __bf16* Als = Asm + (t & 1) * 16384;
        const __bf16* Bls = (__bf16*)Bbase + (t & 1) * 16384;
        bf16x8 af0[4][2], af1[4][2], bfr[2][2];
        // ---- ph0: MH0 x NH0 ---- (af0 loaded once, lives through ph1)
        LOAD_A(af0, 0);
        LOAD_B(bfr, 0);
        if (t + 1 < T) { STAGE_AQ(1, t + 1); STAGE_AQ(3, t + 1); }
        PH_SYNC_PRE;
        __builtin_amdgcn_s_setprio(1);
        MFMA_QUAD(af0, bfr, 0, 0);
        __builtin_amdgcn_s_setprio(0);
        PH_SYNC_POST;
        // ---- ph1: MH0 x NH1 ---- (reuse af0)
        LOAD_B(bfr, 1);
        if (t + 1 < T) STAGE_BS(1, t + 1);
        PH_SYNC_PRE;
        __builtin_amdgcn_s_setprio(1);
        MFMA_QUAD(af0, bfr, 0, 2);
        __builtin_amdgcn_s_setprio(0);
        PH_SYNC_POST;
        // ---- ph2: MH1 x NH0 ---- (af1 loaded once, lives through ph3)
        LOAD_A(af1, 1);
        LOAD_B(bfr, 0);
        if (t + 2 < T) { STAGE_AQ(0, t + 2); STAGE_AQ(2, t + 2); }
        PH_SYNC_PRE;
        __builtin_amdgcn_s_setprio(1);
        MFMA_QUAD(af1, bfr, 4, 0);
        __builtin_amdgcn_s_setprio(0);
        PH_SYNC_POST;
        // ---- ph3: MH1 x NH1 ---- (reuse af1)
        LOAD_B(bfr, 1);
        if (t + 2 < T) STAGE_BS(0, t + 2);
        PH_SYNC_PRE;
        __builtin_amdgcn_s_setprio(1);
        MFMA_QUAD(af1, bfr, 4, 2);
        __builtin_amdgcn_s_setprio(0);
        if (t + 2 < T)      { asm volatile("s_waitcnt vmcnt(4)" ::: "memory"); }
        else if (t + 1 < T) { asm volatile("s_waitcnt vmcnt(0)" ::: "memory"); }
        PH_SYNC_POST;
    }
#undef PH_SYNC_PRE
#undef PH_SYNC_POST
#undef MFMA_QUAD
#undef LOAD_A
#undef LOAD_B
#undef STAGE_AQ
#undef STAGE_BS

#pragma unroll
    for (int mi = 0; mi < 8; ++mi)
#pragma unroll
        for (int ni = 0; ni < 4; ++ni)
#pragma unroll
            for (int r = 0; r < 4; ++r)
                C[(size_t)(m0 + wr * 128 + mi * 16 + l4 * 4 + r) * N
                  + n0 + wc * 64 + ni * 16 + l15] = (OUT)acc[mi][ni][r];
}

// ---------------- RoPE apply: qkv bf16 -> Q (pre-scaled) [B,32,S,128], K [B,8,S,128] bf16 ----------------
__global__ __launch_bounds__(256) void rope_kernel(const __bf16* __restrict__ qkv,
                                                   const int* __restrict__ pos,
                                                   const float* __restrict__ ct,
                                                   const float* __restrict__ st,
                                                   __bf16* __restrict__ Qb,
                                                   __bf16* __restrict__ Kb) {
    const int tid = threadIdx.x;
    const int tok = blockIdx.x;                 // 0..B*S-1
    const int b = tok >> 11, s = tok & 2047;
    const int p = pos[tok];
    const __bf16* base = qkv + (size_t)tok * QKVSZ;
    const float* cb = ct + (size_t)p * 64;
    const float* sb = st + (size_t)p * 64;
    for (int idx = tid; idx < 2560; idx += 256) {   // (32+8)*64 pairs
        int head = idx >> 6, i = idx & 63;
        float c = cb[i], sn = sb[i];
        if (head < 32) {
            float x1 = (float)base[head * HDIM + i];
            float x2 = (float)base[head * HDIM + 64 + i];
            size_t o = ((size_t)(b * 32 + head) * S_LEN + s) * HDIM + i;
            Qb[o]      = (__bf16)((x1 * c - x2 * sn) * ATT_SCALE);
            Qb[o + 64] = (__bf16)((x2 * c + x1 * sn) * ATT_SCALE);
        } else {
            int g = head - 32;
            float x1 = (float)base[QSZ + g * HDIM + i];
            float x2 = (float)base[QSZ + g * HDIM + 64 + i];
            size_t o = ((size_t)(b * 8 + g) * S_LEN + s) * HDIM + i;
            Kb[o]      = (__bf16)(x1 * c - x2 * sn);
            Kb[o + 64] = (__bf16)(x2 * c + x1 * sn);
        }
    }
}

// ---------------- V transpose: qkv bf16 V-slice -> Vt [B,8,128,S] bf16 ----------------
__global__ __launch_bounds__(256) void vtrans_kernel(const __bf16* __restrict__ qkv,
                                                     __bf16* __restrict__ Vt) {
    __shared__ __bf16 T[64][132];
    const int tid = threadIdx.x;
    const int st = blockIdx.x, g = blockIdx.y, b = blockIdx.z;
    const __bf16* src = qkv + ((size_t)(b * S_LEN + st * 64)) * QKVSZ + (QSZ + KVSZ) + g * HDIM;
#pragma unroll
    for (int it = 0; it < 8; ++it) {
        int c = it * 256 + tid;       // 0..2047, 32 4-elem chunks per row
        int row = c >> 5;
        int c4 = c & 31;
        bf16x4 v = *(const bf16x4*)(src + (size_t)row * QKVSZ + c4 * 4);
        *(bf16x4*)(&T[row][c4 * 4]) = v;
    }
    __syncthreads();
#pragma unroll
    for (int it = 0; it < 8; ++it) {
        int c = it * 256 + tid;       // 0..2047, 16 chunks (of 4 s-cols) per d-row
        int d = c >> 4;
        int s4 = (c & 15) * 4;
        bf16x4 o;
        o[0] = T[s4 + 0][d]; o[1] = T[s4 + 1][d]; o[2] = T[s4 + 2][d]; o[3] = T[s4 + 3][d];
        *(bf16x4*)(Vt + ((size_t)(b * 8 + g) * HDIM + d) * S_LEN + st * 64 + s4) = o;
    }
}

// ---------------- Flash attention (causal, GQA rep=4) ----------------
// QBLK=128 (4 waves x 32 q-rows), KVBLK=64. Swapped QK^T (mfma(K,Q)),
// lane-local softmax, defer-max. K/V double-buffered swizzled LDS (64KB) +
// P buffer [4][32][64] XOR-swizzled (16KB) = 81920 B -> 2 blocks/CU.
__global__ __launch_bounds__(256, 2) void attn_kernel(const __bf16* __restrict__ Q,
                                                      const __bf16* __restrict__ K,
                                                      const __bf16* __restrict__ Vt,
                                                      __bf16* __restrict__ O) {
    const int tid = threadIdx.x;
    const int w = tid >> 6, l = tid & 63;
    const int l15 = l & 15, l4 = l >> 4;
    const int qt = gridDim.x - 1 - blockIdx.x;   // reversed: long blocks first
    const int h = blockIdx.y, b = blockIdx.z;
    const int g = h >> 2;
    const int qw0 = qt * 128 + w * 32;           // wave's first q-row

    __shared__ __bf16 Ks[2][64 * 128];   // 2x16 KB; chunk c: row=c>>4, cc=(c&15)^(row&7)
    __shared__ __bf16 Vs[2][128 * 64];   // 2x16 KB; chunk c: row=c>>3, cc=(c&7)^(row&7)
    __shared__ __bf16 Pl[4 * 32 * 64];   // 16 KB; per-wave P[q][chunk^((q&3)<<2)]

    const __bf16* Qp = Q + ((size_t)((b * 32 + h) * S_LEN + qw0)) * HDIM;
    const __bf16* Kp = K + (size_t)(b * 8 + g) * S_LEN * HDIM;
    const __bf16* Vp = Vt + (size_t)(b * 8 + g) * HDIM * S_LEN;

    bf16x8 qf[2][4];
#pragma unroll
    for (int qh = 0; qh < 2; ++qh)
#pragma unroll
        for (int kk = 0; kk < 4; ++kk)
            qf[qh][kk] = *(const bf16x8*)(Qp + (size_t)(qh * 16 + l15) * HDIM + kk * 32 + l4 * 8);

    f32x4 acc[2][8] = {};
    float m[2]    = {-1e30f, -1e30f};
    float lsum[2] = {0.f, 0.f};

#define STAGE(buf, ktile) do {                                                     \
        const __bf16* kbase = Kp + (size_t)(ktile) * 64 * HDIM;                    \
        _Pragma("unroll")                                                          \
        for (int i_ = 0; i_ < 4; ++i_) {                                           \
            int c_ = i_ * 256 + tid;            /* 1024 chunks = 64x128 bf16 */    \
            int row_ = c_ >> 4, cc_ = (c_ & 15) ^ (row_ & 7);                      \
            GLDS16(kbase + (size_t)row_ * HDIM + cc_ * 8,                          \
                   (char*)Ks[buf] + c_ * 16);                                      \
        }                                                                          \
        const __bf16* vbase = Vp + (size_t)(ktile) * 64;                           \
        _Pragma("unroll")                                                          \
        for (int i_ = 0; i_ < 4; ++i_) {                                           \
            int c_ = i_ * 256 + tid;            /* 1024 chunks = 128x64 bf16 */    \
            int row_ = c_ >> 3, cc_ = (c_ & 7) ^ (row_ & 7);                       \
            GLDS16(vbase + (size_t)row_ * S_LEN + cc_ * 8,                         \
                   (char*)Vs[buf] + c_ * 16);                                      \
        }                                                                          \
    } while (0)

    const int nkt = 2 * qt + 2;
    int cur = 0;
    STAGE(0, 0);
    __syncthreads();   // drains vmcnt(0): tile 0 ready

    for (int kt = 0; kt < nkt; ++kt) {
        if (kt + 1 < nkt) STAGE(cur ^ 1, kt + 1);   // prefetch next tile
        if (kt * 64 <= qw0 + 31) {                  // wave-level causal skip
            // ---- scores (swapped): S[k = fn*16 + l4*4 + r][q = qw0 + qh*16 + l15] ----
            f32x4 sfr[2][4];
            __builtin_amdgcn_s_setprio(1);
#pragma unroll
            for (int fn = 0; fn < 4; ++fn) {
                f32x4 sa0 = {}, sa1 = {};
#pragma unroll
                for (int kk = 0; kk < 4; ++kk) {
                    int row = fn * 16 + l15;
                    int cc = (kk * 4 + l4) ^ (l15 & 7);
                    bf16x8 kb = *(const bf16x8*)(Ks[cur] + row * HDIM + cc * 8);
                    sa0 = __builtin_amdgcn_mfma_f32_16x16x32_bf16(kb, qf[0][kk], sa0, 0, 0, 0);
                    sa1 = __builtin_amdgcn_mfma_f32_16x16x32_bf16(kb, qf[1][kk], sa1, 0, 0, 0);
                }
                sfr[0][fn] = sa0; sfr[1][fn] = sa1;
            }
            __builtin_amdgcn_s_setprio(0);
            const bool needmask = (kt * 64 + 63 > qw0);
#pragma unroll
            for (int qh = 0; qh < 2; ++qh) {
                const int qrow = qw0 + qh * 16 + l15;
                float pmax = -1e30f;
#pragma unroll
                for (int fn = 0; fn < 4; ++fn)
#pragma unroll
                    for (int r = 0; r < 4; ++r) {
                        float v = sfr[qh][fn][r];
                        if (needmask) {
                            int kcol = kt * 64 + fn * 16 + l4 * 4 + r;
                            if (kcol > qrow) v = -1e30f;
                        }
                        sfr[qh][fn][r] = v;
                        pmax = fmaxf(pmax, v);
                    }
                pmax = fmaxf(pmax, __shfl_xor(pmax, 16));
                pmax = fmaxf(pmax, __shfl_xor(pmax, 32));
                if (!__all(pmax - m[qh] <= 8.0f)) {          // defer-max
                    float mn = fmaxf(m[qh], pmax);
                    float alpha = exp2f((m[qh] - mn) * L2E);
                    m[qh] = mn;
                    lsum[qh] *= alpha;
#pragma unroll
                    for (int r = 0; r < 4; ++r) {
                        float ar = __shfl(alpha, l4 * 4 + r, 16);
#pragma unroll
                        for (int n = 0; n < 8; ++n) acc[qh][n][r] *= ar;
                    }
                }
                float rs = 0.f;
#pragma unroll
                for (int fn = 0; fn < 4; ++fn) {
                    bf16x4 pk;
#pragma unroll
                    for (int r = 0; r < 4; ++r) {
                        float p = exp2f((sfr[qh][fn][r] - m[qh]) * L2E);
                        rs += p;
                        pk[r] = (__bf16)p;
                    }
                    *(bf16x4*)(Pl + w * 2048 + (qh * 16 + l15) * 64
                               + (((fn * 4 + l4) ^ ((l15 & 3) << 2)) * 4)) = pk;
                }
                rs += __shfl_xor(rs, 16);
                rs += __shfl_xor(rs, 32);
                lsum[qh] += rs;
            }
            asm volatile("s_waitcnt lgkmcnt(0)" ::: "memory");
            __builtin_amdgcn_sched_barrier(0);
            // ---- PV ----
            __builtin_amdgcn_s_setprio(1);
#pragma unroll
            for (int kk = 0; kk < 2; ++kk) {
                int pc = ((kk * 8 + l4 * 2) ^ ((l15 & 3) << 2)) * 4;
                bf16x8 pa0 = *(const bf16x8*)(Pl + w * 2048 + l15 * 64 + pc);
                bf16x8 pa1 = *(const bf16x8*)(Pl + w * 2048 + (16 + l15) * 64 + pc);
#pragma unroll
                for (int n = 0; n < 8; ++n) {
                    int row = n * 16 + l15;
                    int cc = (kk * 4 + l4) ^ (l15 & 7);
                    bf16x8 vb = *(const bf16x8*)(Vs[cur] + row * 64 + cc * 8);
                    acc[0][n] = __builtin_amdgcn_mfma_f32_16x16x32_bf16(pa0, vb, acc[0][n], 0, 0, 0);
                    acc[1][n] = __builtin_amdgcn_mfma_f32_16x16x32_bf16(pa1, vb, acc[1][n], 0, 0, 0);
                }
            }
            __builtin_amdgcn_s_setprio(0);
        }
        __syncthreads();   // drains vmcnt(0) (next tile ready) + lgkmcnt
        cur ^= 1;
    }
#undef STAGE
    // ---- epilogue: attn[b, row, h*128 + d] ----
#pragma unroll
    for (int qh = 0; qh < 2; ++qh)
#pragma unroll
        for (int r = 0; r < 4; ++r) {
            float inv = 1.0f / __shfl(lsum[qh], l4 * 4 + r, 16);
            int row = qw0 + qh * 16 + l4 * 4 + r;
#pragma unroll
            for (int n = 0; n < 8; ++n)
                O[((size_t)(b * S_LEN) + row) * QSZ + h * HDIM + n * 16 + l15] = (__bf16)(acc[qh][n][r] * inv);
        }
}

extern "C" void kernel_launch(void* const* d_in, const int* in_sizes, int n_in,
                              void* d_out, int out_size, void* d_ws, size_t ws_size,
                              hipStream_t stream) {
    const int*   pos    = (const int*)d_in[0];
    const float* hidden = (const float*)d_in[1];
    const float* wqkv   = (const float*)d_in[2];
    const float* wo     = (const float*)d_in[3];
    float* out = (float*)d_out;

    // workspace carve
    __bf16* hb    = (__bf16*)d_ws;                     // 16,777,216 elems
    __bf16* wqb   = hb  + 16777216;                    // 25,165,824
    __bf16* wob   = wqb + 25165824;                    // 16,777,216
    __bf16* qkv   = wob + 16777216;                    // 25,165,824 bf16
    __bf16* Qb    = qkv + 25165824;                    // 16,777,216
    __bf16* Kb    = Qb  + 16777216;                    // 4,194,304
    __bf16* Vtb   = Kb  + 4194304;                     // 4,194,304
    __bf16* attnb = Vtb + 4194304;                     // 16,777,216
    float*  rc    = (float*)(attnb + 16777216);        // 131,072
    float*  rs    = rc + 131072;                       // 131,072

    conv_f32_bf16<<<16384, 256, 0, stream>>>(hidden, hb, 4194304);
    conv_f32_bf16<<<24576, 256, 0, stream>>>(wqkv, wqb, 6291456);
    conv_f32_bf16<<<16384, 256, 0, stream>>>(wo, wob, 4194304);
    rope_table_kernel<<<512, 256, 0, stream>>>(rc, rs);
    gemm256<__bf16><<<dim3(QKVSZ / 256, (B_DIM * S_LEN) / 256), 512, 0, stream>>>(hb, wqb, qkv, QKVSZ);
    rope_kernel<<<B_DIM * S_LEN, 256, 0, stream>>>(qkv, pos, rc, rs, Qb, Kb);
    vtrans_kernel<<<dim3(S_LEN / 64, NKV, B_DIM), 256, 0, stream>>>(qkv, Vtb);
    attn_kernel<<<dim3(S_LEN / 128, NHEADS, B_DIM), 256, 0, stream>>>(Qb, Kb, Vtb, attnb);
    gemm256<float><<<dim3(HIDDEN / 256, (B_DIM * S_LEN) / 256), 512, 0, stream>>>(attnb, wob, out, HIDDEN);
}